// Round 1
// baseline (3846.807 us; speedup 1.0000x reference)
//
#include <hip/hip_runtime.h>

#define NB 16
#define NS 12
#define NN 2048
#define HD 64
#define NE 32768
#define NROWS (NB*NN)          // 32768 rows of 64
#define DTC  0.1f
#define DT2C 0.05f
#define DT6C (0.1f/6.0f)

// ---------------- init: y0 = inputs[:,0] @ w_in + b_in ----------------
__global__ __launch_bounds__(256) void init_y_k(const float* __restrict__ inputs,
    const float* __restrict__ w_in, const float* __restrict__ b_in, float* __restrict__ y)
{
    int idx = blockIdx.x * 256 + threadIdx.x;     // < NROWS*64
    int hh = idx & 63;
    int bn = idx >> 6;
    int b = bn >> 11, n = bn & (NN - 1);
    const float* ip = inputs + ((size_t)(b * NS) * NN + n) * 2;
    y[idx] = ip[0] * w_in[hh] + ip[1] * w_in[64 + hh] + b_in[hh];
}

// ---------------- CSR build (once per launch) ----------------
__global__ __launch_bounds__(256) void zero_deg_k(int* __restrict__ deg)
{
    int i = blockIdx.x * 256 + threadIdx.x;
    if (i < NN) deg[i] = 0;
}
__global__ __launch_bounds__(256) void count_deg_k(const int* __restrict__ dst, int* __restrict__ deg)
{
    int e = blockIdx.x * 256 + threadIdx.x;
    if (e < NE) atomicAdd(&deg[dst[e]], 1);
}
__global__ __launch_bounds__(1024) void scan_k(const int* __restrict__ deg,
    int* __restrict__ offs, int* __restrict__ cursor)
{
    __shared__ int p[1024];
    int t = threadIdx.x;
    int d0 = deg[2 * t], d1 = deg[2 * t + 1];
    p[t] = d0 + d1;
    __syncthreads();
    for (int d = 1; d < 1024; d <<= 1) {
        int v = (t >= d) ? p[t - d] : 0;
        __syncthreads();
        p[t] += v;
        __syncthreads();
    }
    int excl = (t > 0) ? p[t - 1] : 0;     // exclusive pair-sum
    offs[2 * t] = excl;       offs[2 * t + 1] = excl + d0;
    cursor[2 * t] = excl;     cursor[2 * t + 1] = excl + d0;
    if (t == 1023) offs[2048] = p[1023];
}
__global__ __launch_bounds__(256) void scatter_k(const int* __restrict__ src, const int* __restrict__ dst,
    int* __restrict__ cursor, int* __restrict__ csr)
{
    int e = blockIdx.x * 256 + threadIdx.x;
    if (e < NE) {
        int pos = atomicAdd(&cursor[dst[e]], 1);
        csr[pos] = src[e];
    }
}

// ---------------- GEMM stage: z = y (+c*k [+RK4 combine]); h = z@Wh; e_s,e_d ----------------
// mode 0: z = y                        (very first eval)
// mode 1: z = y + 0.5dt*k ; acc  = k   (stage2, k==k1)
// mode 2: z = y + 0.5dt*k ; acc += 2k  (stage3, k==k2)
// mode 3: z = y + dt*k    ; acc += 2k  (stage4, k==k3)
// mode 4: z = y + dt/6*(acc+k); y = z  (stage1 of steps 1..11, k==k4)
__global__ __launch_bounds__(256) void gemm_k(
    const float* yin, const float* __restrict__ kc, float* __restrict__ acc,
    float* yout,
    const float* __restrict__ Wh, const float* __restrict__ a_src, const float* __restrict__ a_dst,
    float* __restrict__ h, float* __restrict__ es, float* __restrict__ ed, int mode)
{
    __shared__ float Zs[64 * 65];              // Zs[k][r], pad 65
    int t = threadIdx.x;
    int row0 = blockIdx.x * 64;
    const float4* y4 = (const float4*)(yin + (size_t)row0 * 64);
    const float4* k4 = (const float4*)(kc + (size_t)row0 * 64);
    float4* a4 = (float4*)(acc + (size_t)row0 * 64);
    float4* yo4 = (float4*)(yout + (size_t)row0 * 64);

#pragma unroll
    for (int i = 0; i < 4; i++) {
        int flat = t + 256 * i;                // float4 index in [0,1024)
        float4 z = y4[flat];
        if (mode == 1) {
            float4 kv = k4[flat];
            a4[flat] = kv;
            z.x += DT2C * kv.x; z.y += DT2C * kv.y; z.z += DT2C * kv.z; z.w += DT2C * kv.w;
        } else if (mode == 2) {
            float4 kv = k4[flat];
            float4 av = a4[flat];
            av.x += 2.f * kv.x; av.y += 2.f * kv.y; av.z += 2.f * kv.z; av.w += 2.f * kv.w;
            a4[flat] = av;
            z.x += DT2C * kv.x; z.y += DT2C * kv.y; z.z += DT2C * kv.z; z.w += DT2C * kv.w;
        } else if (mode == 3) {
            float4 kv = k4[flat];
            float4 av = a4[flat];
            av.x += 2.f * kv.x; av.y += 2.f * kv.y; av.z += 2.f * kv.z; av.w += 2.f * kv.w;
            a4[flat] = av;
            z.x += DTC * kv.x; z.y += DTC * kv.y; z.z += DTC * kv.z; z.w += DTC * kv.w;
        } else if (mode == 4) {
            float4 kv = k4[flat];
            float4 av = a4[flat];
            z.x += DT6C * (av.x + kv.x); z.y += DT6C * (av.y + kv.y);
            z.z += DT6C * (av.z + kv.z); z.w += DT6C * (av.w + kv.w);
            yo4[flat] = z;
        }
        int r = flat >> 4;
        int kkb = (flat & 15) << 2;
        Zs[(kkb + 0) * 65 + r] = z.x;
        Zs[(kkb + 1) * 65 + r] = z.y;
        Zs[(kkb + 2) * 65 + r] = z.z;
        Zs[(kkb + 3) * 65 + r] = z.w;
    }
    __syncthreads();

    int lane = t & 63;
    int g = t >> 6;                            // head / j-group (wave-uniform)
    const float* whg = Wh + g * 16;
    float a[16];
#pragma unroll
    for (int j = 0; j < 16; j++) a[j] = 0.f;

    for (int kk = 0; kk < 64; kk++) {
        float zk = Zs[kk * 65 + lane];
        const float4* w4 = (const float4*)(whg + kk * 64);
        float4 w0 = w4[0], w1v = w4[1], w2v = w4[2], w3v = w4[3];
        a[0] += zk * w0.x;  a[1] += zk * w0.y;  a[2] += zk * w0.z;  a[3] += zk * w0.w;
        a[4] += zk * w1v.x; a[5] += zk * w1v.y; a[6] += zk * w1v.z; a[7] += zk * w1v.w;
        a[8] += zk * w2v.x; a[9] += zk * w2v.y; a[10] += zk * w2v.z; a[11] += zk * w2v.w;
        a[12] += zk * w3v.x; a[13] += zk * w3v.y; a[14] += zk * w3v.z; a[15] += zk * w3v.w;
    }

    int row = row0 + lane;
    float4* h4 = (float4*)(h + (size_t)row * 64 + g * 16);
    h4[0] = make_float4(a[0], a[1], a[2], a[3]);
    h4[1] = make_float4(a[4], a[5], a[6], a[7]);
    h4[2] = make_float4(a[8], a[9], a[10], a[11]);
    h4[3] = make_float4(a[12], a[13], a[14], a[15]);

    const float4* as4 = (const float4*)(a_src + g * 16);
    const float4* ad4 = (const float4*)(a_dst + g * 16);
    float4 s0 = as4[0], s1 = as4[1], s2 = as4[2], s3 = as4[3];
    float4 d0 = ad4[0], d1 = ad4[1], d2 = ad4[2], d3 = ad4[3];
    float sacc = a[0] * s0.x + a[1] * s0.y + a[2] * s0.z + a[3] * s0.w
               + a[4] * s1.x + a[5] * s1.y + a[6] * s1.z + a[7] * s1.w
               + a[8] * s2.x + a[9] * s2.y + a[10] * s2.z + a[11] * s2.w
               + a[12] * s3.x + a[13] * s3.y + a[14] * s3.z + a[15] * s3.w;
    float dacc = a[0] * d0.x + a[1] * d0.y + a[2] * d0.z + a[3] * d0.w
               + a[4] * d1.x + a[5] * d1.y + a[6] * d1.z + a[7] * d1.w
               + a[8] * d2.x + a[9] * d2.y + a[10] * d2.z + a[11] * d2.w
               + a[12] * d3.x + a[13] * d3.y + a[14] * d3.z + a[15] * d3.w;
    es[row * 4 + g] = sacc;
    ed[row * 4 + g] = dacc;
}

// ---------------- per-node online-softmax aggregation ----------------
__global__ __launch_bounds__(256) void gat_agg_k(
    const float* __restrict__ h, const float* __restrict__ es, const float* __restrict__ ed,
    const int* __restrict__ offs, const int* __restrict__ csr,
    const float* __restrict__ bias_g, float* __restrict__ kout)
{
    int w = (blockIdx.x << 2) + (threadIdx.x >> 6);   // (b,n) index in [0,32768)
    int lane = threadIdx.x & 63;
    int b = w >> 11, n = w & (NN - 1);
    int base = b * NN;
    int o0 = offs[n], o1 = offs[n + 1];
    float edv = ed[(size_t)(base + n) * 4 + (lane >> 4)];
    float m = -INFINITY, den = 0.f, accv = 0.f;
    for (int i = o0; i < o1; i++) {
        int s = __builtin_amdgcn_readfirstlane(csr[i]);
        float esv = es[(size_t)(base + s) * 4 + (lane >> 4)];
        float e = esv + edv;
        e = fmaxf(e, 0.2f * e);                       // leaky_relu, slope<1
        float hv = h[(size_t)(base + s) * 64 + lane];
        float nm = fmaxf(m, e);
        float sc = __expf(m - nm);                    // first iter: exp(-inf)=0
        float wv = __expf(e - nm);
        den = den * sc + wv;
        accv = accv * sc + wv * hv;
        m = nm;
    }
    float outv = (o1 > o0) ? accv / den : 0.f;
    kout[(size_t)(base + n) * 64 + lane] = outv + bias_g[lane];
}

// ---------------- final: y' = y + dt/6(acc+k4); out = tanh(y'@w1+b1)@w2+b2 ----------------
__global__ __launch_bounds__(256) void mlp_k(
    const float* __restrict__ yin, const float* __restrict__ kc, const float* __restrict__ acc,
    const float* __restrict__ w1, const float* __restrict__ b1,
    const float* __restrict__ w2, const float* __restrict__ b2,
    float* __restrict__ out)
{
    __shared__ float Zs[64 * 65];
    __shared__ float Ts[64 * 65];
    int t = threadIdx.x;
    int row0 = blockIdx.x * 64;
    const float4* y4 = (const float4*)(yin + (size_t)row0 * 64);
    const float4* k4 = (const float4*)(kc + (size_t)row0 * 64);
    const float4* a4 = (const float4*)(acc + (size_t)row0 * 64);
#pragma unroll
    for (int i = 0; i < 4; i++) {
        int flat = t + 256 * i;
        float4 z = y4[flat];
        float4 kv = k4[flat];
        float4 av = a4[flat];
        z.x += DT6C * (av.x + kv.x); z.y += DT6C * (av.y + kv.y);
        z.z += DT6C * (av.z + kv.z); z.w += DT6C * (av.w + kv.w);
        int r = flat >> 4;
        int kkb = (flat & 15) << 2;
        Zs[(kkb + 0) * 65 + r] = z.x;
        Zs[(kkb + 1) * 65 + r] = z.y;
        Zs[(kkb + 2) * 65 + r] = z.z;
        Zs[(kkb + 3) * 65 + r] = z.w;
    }
    __syncthreads();

    int lane = t & 63;
    int g = t >> 6;
    float a[16];
#pragma unroll
    for (int j = 0; j < 16; j++) a[j] = 0.f;
    const float* w1g = w1 + g * 16;
    for (int kk = 0; kk < 64; kk++) {
        float zk = Zs[kk * 65 + lane];
        const float4* w4 = (const float4*)(w1g + kk * 64);
        float4 w0 = w4[0], w1v = w4[1], w2v = w4[2], w3v = w4[3];
        a[0] += zk * w0.x;  a[1] += zk * w0.y;  a[2] += zk * w0.z;  a[3] += zk * w0.w;
        a[4] += zk * w1v.x; a[5] += zk * w1v.y; a[6] += zk * w1v.z; a[7] += zk * w1v.w;
        a[8] += zk * w2v.x; a[9] += zk * w2v.y; a[10] += zk * w2v.z; a[11] += zk * w2v.w;
        a[12] += zk * w3v.x; a[13] += zk * w3v.y; a[14] += zk * w3v.z; a[15] += zk * w3v.w;
    }
    const float4* b1g = (const float4*)(b1 + g * 16);
    float4 bb0 = b1g[0], bb1 = b1g[1], bb2 = b1g[2], bb3 = b1g[3];
    float bb[16] = { bb0.x,bb0.y,bb0.z,bb0.w, bb1.x,bb1.y,bb1.z,bb1.w,
                     bb2.x,bb2.y,bb2.z,bb2.w, bb3.x,bb3.y,bb3.z,bb3.w };
#pragma unroll
    for (int j = 0; j < 16; j++) {
        float v = a[j] + bb[j];
        float ex = __expf(2.f * v);
        float tv = 1.f - 2.f / (ex + 1.f);
        Ts[(16 * g + j) * 65 + lane] = tv;
    }
    __syncthreads();

    float a2[16];
#pragma unroll
    for (int j = 0; j < 16; j++) a2[j] = 0.f;
    const float* w2g = w2 + g * 16;
    for (int kk = 0; kk < 64; kk++) {
        float tk = Ts[kk * 65 + lane];
        const float4* w4 = (const float4*)(w2g + kk * 64);
        float4 w0 = w4[0], w1v = w4[1], w2v = w4[2], w3v = w4[3];
        a2[0] += tk * w0.x;  a2[1] += tk * w0.y;  a2[2] += tk * w0.z;  a2[3] += tk * w0.w;
        a2[4] += tk * w1v.x; a2[5] += tk * w1v.y; a2[6] += tk * w1v.z; a2[7] += tk * w1v.w;
        a2[8] += tk * w2v.x; a2[9] += tk * w2v.y; a2[10] += tk * w2v.z; a2[11] += tk * w2v.w;
        a2[12] += tk * w3v.x; a2[13] += tk * w3v.y; a2[14] += tk * w3v.z; a2[15] += tk * w3v.w;
    }
    const float4* b2g = (const float4*)(b2 + g * 16);
    float4 c0 = b2g[0], c1 = b2g[1], c2 = b2g[2], c3 = b2g[3];
    int row = row0 + lane;
    float4* o4 = (float4*)(out + (size_t)row * 64 + g * 16);
    o4[0] = make_float4(a2[0] + c0.x, a2[1] + c0.y, a2[2] + c0.z, a2[3] + c0.w);
    o4[1] = make_float4(a2[4] + c1.x, a2[5] + c1.y, a2[6] + c1.z, a2[7] + c1.w);
    o4[2] = make_float4(a2[8] + c2.x, a2[9] + c2.y, a2[10] + c2.z, a2[11] + c2.w);
    o4[3] = make_float4(a2[12] + c3.x, a2[13] + c3.y, a2[14] + c3.z, a2[15] + c3.w);
}

extern "C" void kernel_launch(void* const* d_in, const int* in_sizes, int n_in,
                              void* d_out, int out_size, void* d_ws, size_t ws_size,
                              hipStream_t stream)
{
    const float* inputs = (const float*)d_in[0];
    const float* w_in   = (const float*)d_in[1];
    const float* b_in   = (const float*)d_in[2];
    const float* Wh     = (const float*)d_in[3];
    const float* bias_g = (const float*)d_in[4];
    const float* a_src  = (const float*)d_in[5];
    const float* a_dst  = (const float*)d_in[6];
    const float* w1     = (const float*)d_in[7];
    const float* b1     = (const float*)d_in[8];
    const float* w2     = (const float*)d_in[9];
    const float* b2     = (const float*)d_in[10];
    const int* src      = (const int*)d_in[11];
    const int* dst      = (const int*)d_in[12];
    float* out = (float*)d_out;

    float* ws = (float*)d_ws;
    const size_t SZ = (size_t)NROWS * 64;          // 2097152 floats (8 MB)
    float* y   = ws;
    float* acc = y + SZ;
    float* kc  = acc + SZ;
    float* h   = kc + SZ;
    float* es  = h + SZ;
    float* ed  = es + (size_t)NROWS * 4;
    int* offs   = (int*)(ed + (size_t)NROWS * 4);  // 2049 used
    int* cursor = offs + 2064;
    int* deg    = cursor + 2048;
    int* csr    = deg + 2048;                      // NE ints

    init_y_k<<<NROWS * 64 / 256, 256, 0, stream>>>(inputs, w_in, b_in, y);
    zero_deg_k<<<8, 256, 0, stream>>>(deg);
    count_deg_k<<<NE / 256, 256, 0, stream>>>(dst, deg);
    scan_k<<<1, 1024, 0, stream>>>(deg, offs, cursor);
    scatter_k<<<NE / 256, 256, 0, stream>>>(src, dst, cursor, csr);

    for (int step = 0; step < 12; step++) {
        gemm_k<<<512, 256, 0, stream>>>(y, kc, acc, y, Wh, a_src, a_dst, h, es, ed, step == 0 ? 0 : 4);
        gat_agg_k<<<8192, 256, 0, stream>>>(h, es, ed, offs, csr, bias_g, kc);   // k1
        gemm_k<<<512, 256, 0, stream>>>(y, kc, acc, y, Wh, a_src, a_dst, h, es, ed, 1);
        gat_agg_k<<<8192, 256, 0, stream>>>(h, es, ed, offs, csr, bias_g, kc);   // k2
        gemm_k<<<512, 256, 0, stream>>>(y, kc, acc, y, Wh, a_src, a_dst, h, es, ed, 2);
        gat_agg_k<<<8192, 256, 0, stream>>>(h, es, ed, offs, csr, bias_g, kc);   // k3
        gemm_k<<<512, 256, 0, stream>>>(y, kc, acc, y, Wh, a_src, a_dst, h, es, ed, 3);
        gat_agg_k<<<8192, 256, 0, stream>>>(h, es, ed, offs, csr, bias_g, kc);   // k4
    }
    mlp_k<<<512, 256, 0, stream>>>(y, kc, acc, w1, b1, w2, b2, out);
}

// Round 2
// 2171.680 us; speedup vs baseline: 1.7714x; 1.7714x over previous
//
#include <hip/hip_runtime.h>

#define NB 16
#define NS 12
#define NN 2048
#define NE 32768
#define NROWS (NB*NN)          // 32768 rows of 64
#define DTC  0.1f
#define DT2C 0.05f
#define DT6C (0.1f/6.0f)

// ---------------- init: y0 = inputs[:,0] @ w_in + b_in ----------------
__global__ __launch_bounds__(256) void init_y_k(const float* __restrict__ inputs,
    const float* __restrict__ w_in, const float* __restrict__ b_in, float* __restrict__ y)
{
    int idx = blockIdx.x * 256 + threadIdx.x;     // < NROWS*64
    int hh = idx & 63;
    int bn = idx >> 6;
    int b = bn >> 11, n = bn & (NN - 1);
    const float* ip = inputs + ((size_t)(b * NS) * NN + n) * 2;
    y[idx] = ip[0] * w_in[hh] + ip[1] * w_in[64 + hh] + b_in[hh];
}

// ---------------- CSR build (once per launch) ----------------
__global__ __launch_bounds__(256) void zero_deg_k(int* __restrict__ deg)
{
    int i = blockIdx.x * 256 + threadIdx.x;
    if (i < NN) deg[i] = 0;
}
__global__ __launch_bounds__(256) void count_deg_k(const int* __restrict__ dst, int* __restrict__ deg)
{
    int e = blockIdx.x * 256 + threadIdx.x;
    if (e < NE) atomicAdd(&deg[dst[e]], 1);
}
__global__ __launch_bounds__(1024) void scan_k(const int* __restrict__ deg,
    int* __restrict__ offs, int* __restrict__ cursor)
{
    __shared__ int p[1024];
    int t = threadIdx.x;
    int d0 = deg[2 * t], d1 = deg[2 * t + 1];
    p[t] = d0 + d1;
    __syncthreads();
    for (int d = 1; d < 1024; d <<= 1) {
        int v = (t >= d) ? p[t - d] : 0;
        __syncthreads();
        p[t] += v;
        __syncthreads();
    }
    int excl = (t > 0) ? p[t - 1] : 0;     // exclusive pair-sum
    offs[2 * t] = excl;       offs[2 * t + 1] = excl + d0;
    cursor[2 * t] = excl;     cursor[2 * t + 1] = excl + d0;
    if (t == 1023) offs[2048] = p[1023];
}
__global__ __launch_bounds__(256) void scatter_k(const int* __restrict__ src, const int* __restrict__ dst,
    int* __restrict__ cursor, int* __restrict__ csr)
{
    int e = blockIdx.x * 256 + threadIdx.x;
    if (e < NE) {
        int pos = atomicAdd(&cursor[dst[e]], 1);
        csr[pos] = src[e];
    }
}

// ---------------- GEMM stage: z = y (+c*k [+RK4 combine]); h = z@Wh; e_s,e_d ----------------
// Outputs in node-major transposed layouts: ht[(n*16+b)*64+c], est/edt[(n*16+b)*4+head]
// mode 0: z = y
// mode 1: z = y + 0.5dt*k ; acc  = k
// mode 2: z = y + 0.5dt*k ; acc += 2k
// mode 3: z = y + dt*k    ; acc += 2k
// mode 4: z = y + dt/6*(acc+k); y = z
__global__ __launch_bounds__(512) void gemm_k(
    const float* yin, const float* __restrict__ kc, float* __restrict__ acc,
    float* yout,
    const float* __restrict__ Wh, const float* __restrict__ a_src, const float* __restrict__ a_dst,
    float* __restrict__ ht, float* __restrict__ est, float* __restrict__ edt, int mode)
{
    __shared__ float Zs[64 * 65];              // Zs[k][r], pad 65
    __shared__ float Ps[8][64];
    __shared__ float Pd[8][64];
    int t = threadIdx.x;
    int row0 = blockIdx.x * 64;
    const float4* y4 = (const float4*)(yin + (size_t)row0 * 64);
    const float4* k4 = (const float4*)(kc + (size_t)row0 * 64);
    float4* a4 = (float4*)(acc + (size_t)row0 * 64);
    float4* yo4 = (float4*)(yout + (size_t)row0 * 64);

#pragma unroll
    for (int i = 0; i < 2; i++) {
        int flat = t + 512 * i;                // float4 index in [0,1024)
        float4 z = y4[flat];
        if (mode == 1) {
            float4 kv = k4[flat];
            a4[flat] = kv;
            z.x += DT2C * kv.x; z.y += DT2C * kv.y; z.z += DT2C * kv.z; z.w += DT2C * kv.w;
        } else if (mode == 2) {
            float4 kv = k4[flat];
            float4 av = a4[flat];
            av.x += 2.f * kv.x; av.y += 2.f * kv.y; av.z += 2.f * kv.z; av.w += 2.f * kv.w;
            a4[flat] = av;
            z.x += DT2C * kv.x; z.y += DT2C * kv.y; z.z += DT2C * kv.z; z.w += DT2C * kv.w;
        } else if (mode == 3) {
            float4 kv = k4[flat];
            float4 av = a4[flat];
            av.x += 2.f * kv.x; av.y += 2.f * kv.y; av.z += 2.f * kv.z; av.w += 2.f * kv.w;
            a4[flat] = av;
            z.x += DTC * kv.x; z.y += DTC * kv.y; z.z += DTC * kv.z; z.w += DTC * kv.w;
        } else if (mode == 4) {
            float4 kv = k4[flat];
            float4 av = a4[flat];
            z.x += DT6C * (av.x + kv.x); z.y += DT6C * (av.y + kv.y);
            z.z += DT6C * (av.z + kv.z); z.w += DT6C * (av.w + kv.w);
            yo4[flat] = z;
        }
        int r = flat >> 4;
        int kkb = (flat & 15) << 2;
        Zs[(kkb + 0) * 65 + r] = z.x;
        Zs[(kkb + 1) * 65 + r] = z.y;
        Zs[(kkb + 2) * 65 + r] = z.z;
        Zs[(kkb + 3) * 65 + r] = z.w;
    }
    __syncthreads();

    int lane = t & 63;
    int cg = __builtin_amdgcn_readfirstlane(t >> 6);   // col-group (8 cols), wave-uniform SGPR
    const float* wcol = Wh + cg * 8;
    float a[8];
#pragma unroll
    for (int j = 0; j < 8; j++) a[j] = 0.f;

    for (int kk = 0; kk < 64; kk++) {
        float zk = Zs[kk * 65 + lane];
        const float4* w4 = (const float4*)(wcol + kk * 64);
        float4 wa = w4[0], wb = w4[1];
        a[0] += zk * wa.x; a[1] += zk * wa.y; a[2] += zk * wa.z; a[3] += zk * wa.w;
        a[4] += zk * wb.x; a[5] += zk * wb.y; a[6] += zk * wb.z; a[7] += zk * wb.w;
    }

    int row = row0 + lane;
    int b = row >> 11, n = row & (NN - 1);
    size_t tn = ((size_t)n << 4) + b;          // node-major index
    float4* h4 = (float4*)(ht + tn * 64 + cg * 8);
    h4[0] = make_float4(a[0], a[1], a[2], a[3]);
    h4[1] = make_float4(a[4], a[5], a[6], a[7]);

    int head = cg >> 1, seg = (cg & 1) * 8;
    const float* as = a_src + head * 16 + seg;
    const float* ad = a_dst + head * 16 + seg;
    float ps = a[0]*as[0] + a[1]*as[1] + a[2]*as[2] + a[3]*as[3]
             + a[4]*as[4] + a[5]*as[5] + a[6]*as[6] + a[7]*as[7];
    float pd = a[0]*ad[0] + a[1]*ad[1] + a[2]*ad[2] + a[3]*ad[3]
             + a[4]*ad[4] + a[5]*ad[5] + a[6]*ad[6] + a[7]*ad[7];
    Ps[cg][lane] = ps;
    Pd[cg][lane] = pd;
    __syncthreads();
    if (cg < 4) {
        est[tn * 4 + cg] = Ps[2 * cg][lane] + Ps[2 * cg + 1][lane];
        edt[tn * 4 + cg] = Pd[2 * cg][lane] + Pd[2 * cg + 1][lane];
    }
}

// ---------------- per-node online-softmax aggregation, 4 batches per wave ----------------
__global__ __launch_bounds__(256) void gat_agg_k(
    const float* __restrict__ ht, const float* __restrict__ est, const float* __restrict__ edt,
    const int* __restrict__ offs, const int* __restrict__ csr,
    const float* __restrict__ bias_g, float* __restrict__ kout)
{
    int n = blockIdx.x;                               // node
    int b0 = (threadIdx.x >> 6) << 2;                 // batches b0..b0+3
    int lane = threadIdx.x & 63;
    int head = lane >> 4;
    int o0 = offs[n], o1 = offs[n + 1];

    const float* edp = edt + ((size_t)n * 16 + b0) * 4 + head;
    float ed0 = edp[0], ed1 = edp[4], ed2 = edp[8], ed3 = edp[12];
    float m0 = -1e30f, m1 = -1e30f, m2 = -1e30f, m3 = -1e30f;
    float d0 = 0.f, d1 = 0.f, d2 = 0.f, d3 = 0.f;
    float a0 = 0.f, a1 = 0.f, a2 = 0.f, a3 = 0.f;

    for (int i = o0; i < o1; i++) {
        int s = __builtin_amdgcn_readfirstlane(csr[i]);
        const float* ep = est + ((size_t)s * 16 + b0) * 4 + head;
        const float* hp = ht + ((size_t)s * 16 + b0) * 64 + lane;
        float e0 = ep[0] + ed0, e1 = ep[4] + ed1, e2 = ep[8] + ed2, e3 = ep[12] + ed3;
        e0 = fmaxf(e0, 0.2f * e0);
        e1 = fmaxf(e1, 0.2f * e1);
        e2 = fmaxf(e2, 0.2f * e2);
        e3 = fmaxf(e3, 0.2f * e3);
        float h0 = hp[0], h1 = hp[64], h2 = hp[128], h3 = hp[192];
        float nm0 = fmaxf(m0, e0), nm1 = fmaxf(m1, e1), nm2 = fmaxf(m2, e2), nm3 = fmaxf(m3, e3);
        float s0 = __expf(m0 - nm0), s1 = __expf(m1 - nm1), s2 = __expf(m2 - nm2), s3 = __expf(m3 - nm3);
        float w0 = __expf(e0 - nm0), w1 = __expf(e1 - nm1), w2 = __expf(e2 - nm2), w3 = __expf(e3 - nm3);
        d0 = d0 * s0 + w0;  a0 = a0 * s0 + w0 * h0;  m0 = nm0;
        d1 = d1 * s1 + w1;  a1 = a1 * s1 + w1 * h1;  m1 = nm1;
        d2 = d2 * s2 + w2;  a2 = a2 * s2 + w2 * h2;  m2 = nm2;
        d3 = d3 * s3 + w3;  a3 = a3 * s3 + w3 * h3;  m3 = nm3;
    }
    float bg = bias_g[lane];
    float o0v = (o1 > o0) ? a0 / d0 : 0.f;
    float o1v = (o1 > o0) ? a1 / d1 : 0.f;
    float o2v = (o1 > o0) ? a2 / d2 : 0.f;
    float o3v = (o1 > o0) ? a3 / d3 : 0.f;
    kout[((size_t)(b0 + 0) * NN + n) * 64 + lane] = o0v + bg;
    kout[((size_t)(b0 + 1) * NN + n) * 64 + lane] = o1v + bg;
    kout[((size_t)(b0 + 2) * NN + n) * 64 + lane] = o2v + bg;
    kout[((size_t)(b0 + 3) * NN + n) * 64 + lane] = o3v + bg;
}

// ---------------- final: y' = y + dt/6(acc+k4); out = tanh(y'@w1+b1)@w2+b2 ----------------
__global__ __launch_bounds__(256) void mlp_k(
    const float* __restrict__ yin, const float* __restrict__ kc, const float* __restrict__ acc,
    const float* __restrict__ w1, const float* __restrict__ b1,
    const float* __restrict__ w2, const float* __restrict__ b2,
    float* __restrict__ out)
{
    __shared__ float Zs[64 * 65];
    __shared__ float Ts[64 * 65];
    int t = threadIdx.x;
    int row0 = blockIdx.x * 64;
    const float4* y4 = (const float4*)(yin + (size_t)row0 * 64);
    const float4* k4 = (const float4*)(kc + (size_t)row0 * 64);
    const float4* a4 = (const float4*)(acc + (size_t)row0 * 64);
#pragma unroll
    for (int i = 0; i < 4; i++) {
        int flat = t + 256 * i;
        float4 z = y4[flat];
        float4 kv = k4[flat];
        float4 av = a4[flat];
        z.x += DT6C * (av.x + kv.x); z.y += DT6C * (av.y + kv.y);
        z.z += DT6C * (av.z + kv.z); z.w += DT6C * (av.w + kv.w);
        int r = flat >> 4;
        int kkb = (flat & 15) << 2;
        Zs[(kkb + 0) * 65 + r] = z.x;
        Zs[(kkb + 1) * 65 + r] = z.y;
        Zs[(kkb + 2) * 65 + r] = z.z;
        Zs[(kkb + 3) * 65 + r] = z.w;
    }
    __syncthreads();

    int lane = t & 63;
    int g = __builtin_amdgcn_readfirstlane(t >> 6);
    float a[16];
#pragma unroll
    for (int j = 0; j < 16; j++) a[j] = 0.f;
    const float* w1g = w1 + g * 16;
    for (int kk = 0; kk < 64; kk++) {
        float zk = Zs[kk * 65 + lane];
        const float4* w4 = (const float4*)(w1g + kk * 64);
        float4 w0 = w4[0], w1v = w4[1], w2v = w4[2], w3v = w4[3];
        a[0] += zk * w0.x;  a[1] += zk * w0.y;  a[2] += zk * w0.z;  a[3] += zk * w0.w;
        a[4] += zk * w1v.x; a[5] += zk * w1v.y; a[6] += zk * w1v.z; a[7] += zk * w1v.w;
        a[8] += zk * w2v.x; a[9] += zk * w2v.y; a[10] += zk * w2v.z; a[11] += zk * w2v.w;
        a[12] += zk * w3v.x; a[13] += zk * w3v.y; a[14] += zk * w3v.z; a[15] += zk * w3v.w;
    }
    const float4* b1g = (const float4*)(b1 + g * 16);
    float4 bb0 = b1g[0], bb1 = b1g[1], bb2 = b1g[2], bb3 = b1g[3];
    float bb[16] = { bb0.x,bb0.y,bb0.z,bb0.w, bb1.x,bb1.y,bb1.z,bb1.w,
                     bb2.x,bb2.y,bb2.z,bb2.w, bb3.x,bb3.y,bb3.z,bb3.w };
#pragma unroll
    for (int j = 0; j < 16; j++) {
        float v = a[j] + bb[j];
        float ex = __expf(2.f * v);
        float tv = 1.f - 2.f / (ex + 1.f);
        Ts[(16 * g + j) * 65 + lane] = tv;
    }
    __syncthreads();

    float a2[16];
#pragma unroll
    for (int j = 0; j < 16; j++) a2[j] = 0.f;
    const float* w2g = w2 + g * 16;
    for (int kk = 0; kk < 64; kk++) {
        float tk = Ts[kk * 65 + lane];
        const float4* w4 = (const float4*)(w2g + kk * 64);
        float4 w0 = w4[0], w1v = w4[1], w2v = w4[2], w3v = w4[3];
        a2[0] += tk * w0.x;  a2[1] += tk * w0.y;  a2[2] += tk * w0.z;  a2[3] += tk * w0.w;
        a2[4] += tk * w1v.x; a2[5] += tk * w1v.y; a2[6] += tk * w1v.z; a2[7] += tk * w1v.w;
        a2[8] += tk * w2v.x; a2[9] += tk * w2v.y; a2[10] += tk * w2v.z; a2[11] += tk * w2v.w;
        a2[12] += tk * w3v.x; a2[13] += tk * w3v.y; a2[14] += tk * w3v.z; a2[15] += tk * w3v.w;
    }
    const float4* b2g = (const float4*)(b2 + g * 16);
    float4 c0 = b2g[0], c1 = b2g[1], c2 = b2g[2], c3 = b2g[3];
    int row = row0 + lane;
    float4* o4 = (float4*)(out + (size_t)row * 64 + g * 16);
    o4[0] = make_float4(a2[0] + c0.x, a2[1] + c0.y, a2[2] + c0.z, a2[3] + c0.w);
    o4[1] = make_float4(a2[4] + c1.x, a2[5] + c1.y, a2[6] + c1.z, a2[7] + c1.w);
    o4[2] = make_float4(a2[8] + c2.x, a2[9] + c2.y, a2[10] + c2.z, a2[11] + c2.w);
    o4[3] = make_float4(a2[12] + c3.x, a2[13] + c3.y, a2[14] + c3.z, a2[15] + c3.w);
}

extern "C" void kernel_launch(void* const* d_in, const int* in_sizes, int n_in,
                              void* d_out, int out_size, void* d_ws, size_t ws_size,
                              hipStream_t stream)
{
    const float* inputs = (const float*)d_in[0];
    const float* w_in   = (const float*)d_in[1];
    const float* b_in   = (const float*)d_in[2];
    const float* Wh     = (const float*)d_in[3];
    const float* bias_g = (const float*)d_in[4];
    const float* a_src  = (const float*)d_in[5];
    const float* a_dst  = (const float*)d_in[6];
    const float* w1     = (const float*)d_in[7];
    const float* b1     = (const float*)d_in[8];
    const float* w2     = (const float*)d_in[9];
    const float* b2     = (const float*)d_in[10];
    const int* src      = (const int*)d_in[11];
    const int* dst      = (const int*)d_in[12];
    float* out = (float*)d_out;

    float* ws = (float*)d_ws;
    const size_t SZ = (size_t)NROWS * 64;          // 2097152 floats (8 MB)
    float* y   = ws;
    float* acc = y + SZ;
    float* kc  = acc + SZ;
    float* ht  = kc + SZ;
    float* est = ht + SZ;
    float* edt = est + (size_t)NROWS * 4;
    int* offs   = (int*)(edt + (size_t)NROWS * 4); // 2049 used
    int* cursor = offs + 2064;
    int* deg    = cursor + 2048;
    int* csr    = deg + 2048;                      // NE ints

    init_y_k<<<NROWS * 64 / 256, 256, 0, stream>>>(inputs, w_in, b_in, y);
    zero_deg_k<<<8, 256, 0, stream>>>(deg);
    count_deg_k<<<NE / 256, 256, 0, stream>>>(dst, deg);
    scan_k<<<1, 1024, 0, stream>>>(deg, offs, cursor);
    scatter_k<<<NE / 256, 256, 0, stream>>>(src, dst, cursor, csr);

    for (int step = 0; step < 12; step++) {
        gemm_k<<<512, 512, 0, stream>>>(y, kc, acc, y, Wh, a_src, a_dst, ht, est, edt, step == 0 ? 0 : 4);
        gat_agg_k<<<NN, 256, 0, stream>>>(ht, est, edt, offs, csr, bias_g, kc);   // k1
        gemm_k<<<512, 512, 0, stream>>>(y, kc, acc, y, Wh, a_src, a_dst, ht, est, edt, 1);
        gat_agg_k<<<NN, 256, 0, stream>>>(ht, est, edt, offs, csr, bias_g, kc);   // k2
        gemm_k<<<512, 512, 0, stream>>>(y, kc, acc, y, Wh, a_src, a_dst, ht, est, edt, 2);
        gat_agg_k<<<NN, 256, 0, stream>>>(ht, est, edt, offs, csr, bias_g, kc);   // k3
        gemm_k<<<512, 512, 0, stream>>>(y, kc, acc, y, Wh, a_src, a_dst, ht, est, edt, 3);
        gat_agg_k<<<NN, 256, 0, stream>>>(ht, est, edt, offs, csr, bias_g, kc);   // k4
    }
    mlp_k<<<512, 256, 0, stream>>>(y, kc, acc, w1, b1, w2, b2, out);
}

// Round 3
// 1694.014 us; speedup vs baseline: 2.2708x; 1.2820x over previous
//
#include <hip/hip_runtime.h>

#define NB 16
#define NS 12
#define NN 2048
#define NE 32768
#define NROWS (NB*NN)          // 32768 rows of 64
#define DTC  0.1f
#define DT2C 0.05f
#define DT6C (0.1f/6.0f)
#define LOG2E 1.44269504088896f

__device__ __forceinline__ unsigned short f2bf(float f) {
    unsigned int u = __float_as_uint(f);
    u = u + 0x7fffu + ((u >> 16) & 1u);      // RTNE
    return (unsigned short)(u >> 16);
}
__device__ __forceinline__ float bf2f(unsigned short u) {
    return __uint_as_float(((unsigned int)u) << 16);
}
__device__ __forceinline__ float fexp2(float x) {
#if __has_builtin(__builtin_amdgcn_exp2f)
    return __builtin_amdgcn_exp2f(x);
#else
    return __expf(x * 0.69314718056f);
#endif
}

// ---------------- init: y0 = inputs[:,0] @ w_in + b_in ----------------
__global__ __launch_bounds__(256) void init_y_k(const float* __restrict__ inputs,
    const float* __restrict__ w_in, const float* __restrict__ b_in, float* __restrict__ y)
{
    int idx = blockIdx.x * 256 + threadIdx.x;     // < NROWS*64
    int hh = idx & 63;
    int bn = idx >> 6;
    int b = bn >> 11, n = bn & (NN - 1);
    const float* ip = inputs + ((size_t)(b * NS) * NN + n) * 2;
    y[idx] = ip[0] * w_in[hh] + ip[1] * w_in[64 + hh] + b_in[hh];
}

// ---------------- CSR build (once per launch) ----------------
__global__ __launch_bounds__(256) void zero_deg_k(int* __restrict__ deg)
{
    int i = blockIdx.x * 256 + threadIdx.x;
    if (i < NN) deg[i] = 0;
}
__global__ __launch_bounds__(256) void count_deg_k(const int* __restrict__ dst, int* __restrict__ deg)
{
    int e = blockIdx.x * 256 + threadIdx.x;
    if (e < NE) atomicAdd(&deg[dst[e]], 1);
}
__global__ __launch_bounds__(1024) void scan_k(const int* __restrict__ deg,
    int* __restrict__ offs, int* __restrict__ cursor)
{
    __shared__ int p[1024];
    int t = threadIdx.x;
    int d0 = deg[2 * t], d1 = deg[2 * t + 1];
    p[t] = d0 + d1;
    __syncthreads();
    for (int d = 1; d < 1024; d <<= 1) {
        int v = (t >= d) ? p[t - d] : 0;
        __syncthreads();
        p[t] += v;
        __syncthreads();
    }
    int excl = (t > 0) ? p[t - 1] : 0;     // exclusive pair-sum
    offs[2 * t] = excl;       offs[2 * t + 1] = excl + d0;
    cursor[2 * t] = excl;     cursor[2 * t + 1] = excl + d0;
    if (t == 1023) offs[2048] = p[1023];
}
__global__ __launch_bounds__(256) void scatter_k(const int* __restrict__ src, const int* __restrict__ dst,
    int* __restrict__ cursor, int* __restrict__ csr)
{
    int e = blockIdx.x * 256 + threadIdx.x;
    if (e < NE) {
        int pos = atomicAdd(&cursor[dst[e]], 1);
        csr[pos] = src[e];
    }
}

// ---------------- GEMM stage: z = y (+c*k [+RK4 combine]); h = z@Wh; e_s,e_d ----------------
// Outputs: ht bf16 [(n*16+b)*64 + c]; est/edt fp32 [(n*4+head)*16 + b], pre-scaled by LOG2E
// mode 0: z = y
// mode 1: z = y + 0.5dt*k ; acc  = k
// mode 2: z = y + 0.5dt*k ; acc += 2k
// mode 3: z = y + dt*k    ; acc += 2k
// mode 4: z = y + dt/6*(acc+k); y = z
__global__ __launch_bounds__(512) void gemm_k(
    const float* yin, const float* __restrict__ kc, float* __restrict__ acc,
    float* yout,
    const float* __restrict__ Wh, const float* __restrict__ a_src, const float* __restrict__ a_dst,
    unsigned short* __restrict__ ht, float* __restrict__ est, float* __restrict__ edt, int mode)
{
    __shared__ float Zs[64 * 65];              // Zs[k][r], pad 65
    __shared__ float Ps[8][64];
    __shared__ float Pd[8][64];
    int t = threadIdx.x;
    int row0 = blockIdx.x * 64;
    const float4* y4 = (const float4*)(yin + (size_t)row0 * 64);
    const float4* k4 = (const float4*)(kc + (size_t)row0 * 64);
    float4* a4 = (float4*)(acc + (size_t)row0 * 64);
    float4* yo4 = (float4*)(yout + (size_t)row0 * 64);

#pragma unroll
    for (int i = 0; i < 2; i++) {
        int flat = t + 512 * i;                // float4 index in [0,1024)
        float4 z = y4[flat];
        if (mode == 1) {
            float4 kv = k4[flat];
            a4[flat] = kv;
            z.x += DT2C * kv.x; z.y += DT2C * kv.y; z.z += DT2C * kv.z; z.w += DT2C * kv.w;
        } else if (mode == 2) {
            float4 kv = k4[flat];
            float4 av = a4[flat];
            av.x += 2.f * kv.x; av.y += 2.f * kv.y; av.z += 2.f * kv.z; av.w += 2.f * kv.w;
            a4[flat] = av;
            z.x += DT2C * kv.x; z.y += DT2C * kv.y; z.z += DT2C * kv.z; z.w += DT2C * kv.w;
        } else if (mode == 3) {
            float4 kv = k4[flat];
            float4 av = a4[flat];
            av.x += 2.f * kv.x; av.y += 2.f * kv.y; av.z += 2.f * kv.z; av.w += 2.f * kv.w;
            a4[flat] = av;
            z.x += DTC * kv.x; z.y += DTC * kv.y; z.z += DTC * kv.z; z.w += DTC * kv.w;
        } else if (mode == 4) {
            float4 kv = k4[flat];
            float4 av = a4[flat];
            z.x += DT6C * (av.x + kv.x); z.y += DT6C * (av.y + kv.y);
            z.z += DT6C * (av.z + kv.z); z.w += DT6C * (av.w + kv.w);
            yo4[flat] = z;
        }
        int r = flat >> 4;
        int kkb = (flat & 15) << 2;
        Zs[(kkb + 0) * 65 + r] = z.x;
        Zs[(kkb + 1) * 65 + r] = z.y;
        Zs[(kkb + 2) * 65 + r] = z.z;
        Zs[(kkb + 3) * 65 + r] = z.w;
    }
    __syncthreads();

    int lane = t & 63;
    int cg = __builtin_amdgcn_readfirstlane(t >> 6);   // col-group (8 cols), wave-uniform SGPR
    const float* wcol = Wh + cg * 8;
    float a[8];
#pragma unroll
    for (int j = 0; j < 8; j++) a[j] = 0.f;

    for (int kk = 0; kk < 64; kk++) {
        float zk = Zs[kk * 65 + lane];
        const float4* w4 = (const float4*)(wcol + kk * 64);
        float4 wa = w4[0], wb = w4[1];
        a[0] += zk * wa.x; a[1] += zk * wa.y; a[2] += zk * wa.z; a[3] += zk * wa.w;
        a[4] += zk * wb.x; a[5] += zk * wb.y; a[6] += zk * wb.z; a[7] += zk * wb.w;
    }

    int row = row0 + lane;
    int b = row >> 11, n = row & (NN - 1);
    size_t tn = ((size_t)n << 4) + b;          // node-major index
    uint4 pk;
    pk.x = (unsigned int)f2bf(a[0]) | ((unsigned int)f2bf(a[1]) << 16);
    pk.y = (unsigned int)f2bf(a[2]) | ((unsigned int)f2bf(a[3]) << 16);
    pk.z = (unsigned int)f2bf(a[4]) | ((unsigned int)f2bf(a[5]) << 16);
    pk.w = (unsigned int)f2bf(a[6]) | ((unsigned int)f2bf(a[7]) << 16);
    *(uint4*)(ht + tn * 64 + cg * 8) = pk;

    int head = cg >> 1, seg = (cg & 1) * 8;
    const float* as = a_src + head * 16 + seg;
    const float* ad = a_dst + head * 16 + seg;
    float ps = a[0]*as[0] + a[1]*as[1] + a[2]*as[2] + a[3]*as[3]
             + a[4]*as[4] + a[5]*as[5] + a[6]*as[6] + a[7]*as[7];
    float pd = a[0]*ad[0] + a[1]*ad[1] + a[2]*ad[2] + a[3]*ad[3]
             + a[4]*ad[4] + a[5]*ad[5] + a[6]*ad[6] + a[7]*ad[7];
    Ps[cg][lane] = ps;
    Pd[cg][lane] = pd;
    __syncthreads();
    if (cg < 4) {
        float sv = (Ps[2 * cg][lane] + Ps[2 * cg + 1][lane]) * LOG2E;
        float dv = (Pd[2 * cg][lane] + Pd[2 * cg + 1][lane]) * LOG2E;
        est[((size_t)n * 4 + cg) * 16 + b] = sv;
        edt[((size_t)n * 4 + cg) * 16 + b] = dv;
    }
}

// ---------------- per-node softmax aggregation, 4 batches/wave, no max (scores O(10)) -----
__global__ __launch_bounds__(256) void gat_agg_k(
    const unsigned short* __restrict__ ht, const float* __restrict__ est, const float* __restrict__ edt,
    const int* __restrict__ offs, const int* __restrict__ csr,
    const float* __restrict__ bias_g, float* __restrict__ kout)
{
    int n = blockIdx.x;                               // node
    int b0 = (threadIdx.x >> 6) << 2;                 // batches b0..b0+3
    int lane = threadIdx.x & 63;
    int head = lane >> 4;
    int o0 = offs[n], o1 = offs[n + 1];

    float4 edv = *(const float4*)(edt + ((size_t)n * 4 + head) * 16 + b0);
    float d0 = 0.f, d1 = 0.f, d2 = 0.f, d3 = 0.f;
    float a0 = 0.f, a1 = 0.f, a2 = 0.f, a3 = 0.f;

#pragma unroll 2
    for (int i = o0; i < o1; i++) {
        int s = __builtin_amdgcn_readfirstlane(csr[i]);
        float4 ev = *(const float4*)(est + ((size_t)s * 4 + head) * 16 + b0);
        const unsigned short* hp = ht + ((size_t)s * 16 + b0) * 64 + lane;
        float e0 = ev.x + edv.x, e1 = ev.y + edv.y, e2 = ev.z + edv.z, e3 = ev.w + edv.w;
        e0 = fmaxf(e0, 0.2f * e0);
        e1 = fmaxf(e1, 0.2f * e1);
        e2 = fmaxf(e2, 0.2f * e2);
        e3 = fmaxf(e3, 0.2f * e3);
        float w0 = fexp2(e0), w1 = fexp2(e1), w2 = fexp2(e2), w3 = fexp2(e3);
        float h0 = bf2f(hp[0]), h1 = bf2f(hp[64]), h2 = bf2f(hp[128]), h3 = bf2f(hp[192]);
        d0 += w0; d1 += w1; d2 += w2; d3 += w3;
        a0 += w0 * h0; a1 += w1 * h1; a2 += w2 * h2; a3 += w3 * h3;
    }
    float bg = bias_g[lane];
    bool has = (o1 > o0);
    float r0 = has ? __builtin_amdgcn_rcpf(d0) : 0.f;
    float r1 = has ? __builtin_amdgcn_rcpf(d1) : 0.f;
    float r2 = has ? __builtin_amdgcn_rcpf(d2) : 0.f;
    float r3 = has ? __builtin_amdgcn_rcpf(d3) : 0.f;
    kout[((size_t)(b0 + 0) * NN + n) * 64 + lane] = a0 * r0 + bg;
    kout[((size_t)(b0 + 1) * NN + n) * 64 + lane] = a1 * r1 + bg;
    kout[((size_t)(b0 + 2) * NN + n) * 64 + lane] = a2 * r2 + bg;
    kout[((size_t)(b0 + 3) * NN + n) * 64 + lane] = a3 * r3 + bg;
}

// ---------------- final: y' = y + dt/6(acc+k4); out = tanh(y'@w1+b1)@w2+b2 ----------------
__global__ __launch_bounds__(256) void mlp_k(
    const float* __restrict__ yin, const float* __restrict__ kc, const float* __restrict__ acc,
    const float* __restrict__ w1, const float* __restrict__ b1,
    const float* __restrict__ w2, const float* __restrict__ b2,
    float* __restrict__ out)
{
    __shared__ float Zs[64 * 65];
    __shared__ float Ts[64 * 65];
    int t = threadIdx.x;
    int row0 = blockIdx.x * 64;
    const float4* y4 = (const float4*)(yin + (size_t)row0 * 64);
    const float4* k4 = (const float4*)(kc + (size_t)row0 * 64);
    const float4* a4 = (const float4*)(acc + (size_t)row0 * 64);
#pragma unroll
    for (int i = 0; i < 4; i++) {
        int flat = t + 256 * i;
        float4 z = y4[flat];
        float4 kv = k4[flat];
        float4 av = a4[flat];
        z.x += DT6C * (av.x + kv.x); z.y += DT6C * (av.y + kv.y);
        z.z += DT6C * (av.z + kv.z); z.w += DT6C * (av.w + kv.w);
        int r = flat >> 4;
        int kkb = (flat & 15) << 2;
        Zs[(kkb + 0) * 65 + r] = z.x;
        Zs[(kkb + 1) * 65 + r] = z.y;
        Zs[(kkb + 2) * 65 + r] = z.z;
        Zs[(kkb + 3) * 65 + r] = z.w;
    }
    __syncthreads();

    int lane = t & 63;
    int g = __builtin_amdgcn_readfirstlane(t >> 6);
    float a[16];
#pragma unroll
    for (int j = 0; j < 16; j++) a[j] = 0.f;
    const float* w1g = w1 + g * 16;
    for (int kk = 0; kk < 64; kk++) {
        float zk = Zs[kk * 65 + lane];
        const float4* w4 = (const float4*)(w1g + kk * 64);
        float4 w0 = w4[0], w1v = w4[1], w2v = w4[2], w3v = w4[3];
        a[0] += zk * w0.x;  a[1] += zk * w0.y;  a[2] += zk * w0.z;  a[3] += zk * w0.w;
        a[4] += zk * w1v.x; a[5] += zk * w1v.y; a[6] += zk * w1v.z; a[7] += zk * w1v.w;
        a[8] += zk * w2v.x; a[9] += zk * w2v.y; a[10] += zk * w2v.z; a[11] += zk * w2v.w;
        a[12] += zk * w3v.x; a[13] += zk * w3v.y; a[14] += zk * w3v.z; a[15] += zk * w3v.w;
    }
    const float4* b1g = (const float4*)(b1 + g * 16);
    float4 bb0 = b1g[0], bb1 = b1g[1], bb2 = b1g[2], bb3 = b1g[3];
    float bb[16] = { bb0.x,bb0.y,bb0.z,bb0.w, bb1.x,bb1.y,bb1.z,bb1.w,
                     bb2.x,bb2.y,bb2.z,bb2.w, bb3.x,bb3.y,bb3.z,bb3.w };
#pragma unroll
    for (int j = 0; j < 16; j++) {
        float v = a[j] + bb[j];
        float ex = __expf(2.f * v);
        float tv = 1.f - 2.f / (ex + 1.f);
        Ts[(16 * g + j) * 65 + lane] = tv;
    }
    __syncthreads();

    float a2[16];
#pragma unroll
    for (int j = 0; j < 16; j++) a2[j] = 0.f;
    const float* w2g = w2 + g * 16;
    for (int kk = 0; kk < 64; kk++) {
        float tk = Ts[kk * 65 + lane];
        const float4* w4 = (const float4*)(w2g + kk * 64);
        float4 w0 = w4[0], w1v = w4[1], w2v = w4[2], w3v = w4[3];
        a2[0] += tk * w0.x;  a2[1] += tk * w0.y;  a2[2] += tk * w0.z;  a2[3] += tk * w0.w;
        a2[4] += tk * w1v.x; a2[5] += tk * w1v.y; a2[6] += tk * w1v.z; a2[7] += tk * w1v.w;
        a2[8] += tk * w2v.x; a2[9] += tk * w2v.y; a2[10] += tk * w2v.z; a2[11] += tk * w2v.w;
        a2[12] += tk * w3v.x; a2[13] += tk * w3v.y; a2[14] += tk * w3v.z; a2[15] += tk * w3v.w;
    }
    const float4* b2g = (const float4*)(b2 + g * 16);
    float4 c0 = b2g[0], c1 = b2g[1], c2 = b2g[2], c3 = b2g[3];
    int row = row0 + lane;
    float4* o4 = (float4*)(out + (size_t)row * 64 + g * 16);
    o4[0] = make_float4(a2[0] + c0.x, a2[1] + c0.y, a2[2] + c0.z, a2[3] + c0.w);
    o4[1] = make_float4(a2[4] + c1.x, a2[5] + c1.y, a2[6] + c1.z, a2[7] + c1.w);
    o4[2] = make_float4(a2[8] + c2.x, a2[9] + c2.y, a2[10] + c2.z, a2[11] + c2.w);
    o4[3] = make_float4(a2[12] + c3.x, a2[13] + c3.y, a2[14] + c3.z, a2[15] + c3.w);
}

extern "C" void kernel_launch(void* const* d_in, const int* in_sizes, int n_in,
                              void* d_out, int out_size, void* d_ws, size_t ws_size,
                              hipStream_t stream)
{
    const float* inputs = (const float*)d_in[0];
    const float* w_in   = (const float*)d_in[1];
    const float* b_in   = (const float*)d_in[2];
    const float* Wh     = (const float*)d_in[3];
    const float* bias_g = (const float*)d_in[4];
    const float* a_src  = (const float*)d_in[5];
    const float* a_dst  = (const float*)d_in[6];
    const float* w1     = (const float*)d_in[7];
    const float* b1     = (const float*)d_in[8];
    const float* w2     = (const float*)d_in[9];
    const float* b2     = (const float*)d_in[10];
    const int* src      = (const int*)d_in[11];
    const int* dst      = (const int*)d_in[12];
    float* out = (float*)d_out;

    float* ws = (float*)d_ws;
    const size_t SZ = (size_t)NROWS * 64;          // 2097152 floats (8 MB)
    float* y   = ws;
    float* acc = y + SZ;
    float* kc  = acc + SZ;
    unsigned short* htb = (unsigned short*)(kc + SZ);   // SZ bf16 (4 MB)
    float* est = (float*)(htb + SZ);               // 131072 floats
    float* edt = est + (size_t)NROWS * 4;
    int* offs   = (int*)(edt + (size_t)NROWS * 4); // 2049 used
    int* cursor = offs + 2064;
    int* deg    = cursor + 2048;
    int* csr    = deg + 2048;                      // NE ints

    init_y_k<<<NROWS * 64 / 256, 256, 0, stream>>>(inputs, w_in, b_in, y);
    zero_deg_k<<<8, 256, 0, stream>>>(deg);
    count_deg_k<<<NE / 256, 256, 0, stream>>>(dst, deg);
    scan_k<<<1, 1024, 0, stream>>>(deg, offs, cursor);
    scatter_k<<<NE / 256, 256, 0, stream>>>(src, dst, cursor, csr);

    for (int step = 0; step < 12; step++) {
        gemm_k<<<512, 512, 0, stream>>>(y, kc, acc, y, Wh, a_src, a_dst, htb, est, edt, step == 0 ? 0 : 4);
        gat_agg_k<<<NN, 256, 0, stream>>>(htb, est, edt, offs, csr, bias_g, kc);   // k1
        gemm_k<<<512, 512, 0, stream>>>(y, kc, acc, y, Wh, a_src, a_dst, htb, est, edt, 1);
        gat_agg_k<<<NN, 256, 0, stream>>>(htb, est, edt, offs, csr, bias_g, kc);   // k2
        gemm_k<<<512, 512, 0, stream>>>(y, kc, acc, y, Wh, a_src, a_dst, htb, est, edt, 2);
        gat_agg_k<<<NN, 256, 0, stream>>>(htb, est, edt, offs, csr, bias_g, kc);   // k3
        gemm_k<<<512, 512, 0, stream>>>(y, kc, acc, y, Wh, a_src, a_dst, htb, est, edt, 3);
        gat_agg_k<<<NN, 256, 0, stream>>>(htb, est, edt, offs, csr, bias_g, kc);   // k4
    }
    mlp_k<<<512, 256, 0, stream>>>(y, kc, acc, w1, b1, w2, b2, out);
}

// Round 4
// 1583.007 us; speedup vs baseline: 2.4301x; 1.0701x over previous
//
#include <hip/hip_runtime.h>

#define NB 16
#define NS 12
#define NN 2048
#define NE 32768
#define NROWS (NB*NN)          // 32768 rows of 64
#define DTC  0.1f
#define DT2C 0.05f
#define DT6C (0.1f/6.0f)
#define LOG2E 1.44269504088896f

// Internal state layouts are NODE-MAJOR: row tn = n*16 + b.
// ht packed: ushort4 at [(n*4+bg)*64 + c] = bf16 h for batches bg*4..bg*4+3, column c.
// est/edt: [n*64 + b*4 + head], pre-scaled by LOG2E.

__device__ __forceinline__ unsigned short f2bf(float f) {
    unsigned int u = __float_as_uint(f);
    u = u + 0x7fffu + ((u >> 16) & 1u);      // RTNE
    return (unsigned short)(u >> 16);
}
__device__ __forceinline__ float fexp2(float x) {
#if __has_builtin(__builtin_amdgcn_exp2f)
    return __builtin_amdgcn_exp2f(x);
#else
    return __expf(x * 0.69314718056f);
#endif
}

// ---------------- init: y0 = inputs[:,0] @ w_in + b_in (node-major out) ----------------
__global__ __launch_bounds__(256) void init_y_k(const float* __restrict__ inputs,
    const float* __restrict__ w_in, const float* __restrict__ b_in, float* __restrict__ y)
{
    int idx = blockIdx.x * 256 + threadIdx.x;     // < NROWS*64
    int hh = idx & 63;
    int tn = idx >> 6;
    int n = tn >> 4, b = tn & 15;
    const float* ip = inputs + ((size_t)(b * NS) * NN + n) * 2;
    y[idx] = ip[0] * w_in[hh] + ip[1] * w_in[64 + hh] + b_in[hh];
}

// ---------------- CSR build (once per launch) ----------------
__global__ __launch_bounds__(256) void zero_deg_k(int* __restrict__ deg)
{
    int i = blockIdx.x * 256 + threadIdx.x;
    if (i < NN) deg[i] = 0;
}
__global__ __launch_bounds__(256) void count_deg_k(const int* __restrict__ dst, int* __restrict__ deg)
{
    int e = blockIdx.x * 256 + threadIdx.x;
    if (e < NE) atomicAdd(&deg[dst[e]], 1);
}
__global__ __launch_bounds__(1024) void scan_k(const int* __restrict__ deg,
    int* __restrict__ offs, int* __restrict__ cursor)
{
    __shared__ int p[1024];
    int t = threadIdx.x;
    int d0 = deg[2 * t], d1 = deg[2 * t + 1];
    p[t] = d0 + d1;
    __syncthreads();
    for (int d = 1; d < 1024; d <<= 1) {
        int v = (t >= d) ? p[t - d] : 0;
        __syncthreads();
        p[t] += v;
        __syncthreads();
    }
    int excl = (t > 0) ? p[t - 1] : 0;     // exclusive pair-sum
    offs[2 * t] = excl;       offs[2 * t + 1] = excl + d0;
    cursor[2 * t] = excl;     cursor[2 * t + 1] = excl + d0;
    if (t == 1023) offs[2048] = p[1023];
}
__global__ __launch_bounds__(256) void scatter_k(const int* __restrict__ src, const int* __restrict__ dst,
    int* __restrict__ cursor, int* __restrict__ csr)
{
    int e = blockIdx.x * 256 + threadIdx.x;
    if (e < NE) {
        int pos = atomicAdd(&cursor[dst[e]], 1);
        csr[pos] = src[e];
    }
}

// ---------------- GEMM stage (node-major): z = y (+c*k); h = z@Wh; e_s,e_d ----------------
// Block = 64 rows tn0..tn0+63 (4 nodes x 16 batches), 512 threads.
__global__ __launch_bounds__(512) void gemm_k(
    const float* yin, const float* __restrict__ kc, float* __restrict__ acc,
    float* yout,
    const float* __restrict__ Wh, const float* __restrict__ a_src, const float* __restrict__ a_dst,
    uint2* __restrict__ ht4, float* __restrict__ est, float* __restrict__ edt, int mode)
{
    __shared__ float Zs[64 * 65];              // Zs[k][r], pad 65
    __shared__ unsigned int Hs[64 * 33];       // bf16-pair matrix [row][colpair], pad 33
    __shared__ float Ps[8][64];
    __shared__ float Pd[8][64];
    int t = threadIdx.x;
    int row0 = blockIdx.x * 64;
    const float4* y4 = (const float4*)(yin + (size_t)row0 * 64);
    const float4* k4 = (const float4*)(kc + (size_t)row0 * 64);
    float4* a4 = (float4*)(acc + (size_t)row0 * 64);
    float4* yo4 = (float4*)(yout + (size_t)row0 * 64);

#pragma unroll
    for (int i = 0; i < 2; i++) {
        int flat = t + 512 * i;                // float4 index in [0,1024)
        float4 z = y4[flat];
        if (mode == 1) {
            float4 kv = k4[flat];
            a4[flat] = kv;
            z.x += DT2C * kv.x; z.y += DT2C * kv.y; z.z += DT2C * kv.z; z.w += DT2C * kv.w;
        } else if (mode == 2) {
            float4 kv = k4[flat];
            float4 av = a4[flat];
            av.x += 2.f * kv.x; av.y += 2.f * kv.y; av.z += 2.f * kv.z; av.w += 2.f * kv.w;
            a4[flat] = av;
            z.x += DT2C * kv.x; z.y += DT2C * kv.y; z.z += DT2C * kv.z; z.w += DT2C * kv.w;
        } else if (mode == 3) {
            float4 kv = k4[flat];
            float4 av = a4[flat];
            av.x += 2.f * kv.x; av.y += 2.f * kv.y; av.z += 2.f * kv.z; av.w += 2.f * kv.w;
            a4[flat] = av;
            z.x += DTC * kv.x; z.y += DTC * kv.y; z.z += DTC * kv.z; z.w += DTC * kv.w;
        } else if (mode == 4) {
            float4 kv = k4[flat];
            float4 av = a4[flat];
            z.x += DT6C * (av.x + kv.x); z.y += DT6C * (av.y + kv.y);
            z.z += DT6C * (av.z + kv.z); z.w += DT6C * (av.w + kv.w);
            yo4[flat] = z;
        }
        int r = flat >> 4;
        int kkb = (flat & 15) << 2;
        Zs[(kkb + 0) * 65 + r] = z.x;
        Zs[(kkb + 1) * 65 + r] = z.y;
        Zs[(kkb + 2) * 65 + r] = z.z;
        Zs[(kkb + 3) * 65 + r] = z.w;
    }
    __syncthreads();

    int lane = t & 63;
    int cg = __builtin_amdgcn_readfirstlane(t >> 6);   // col-group (8 cols), wave-uniform SGPR
    const float* wcol = Wh + cg * 8;
    float a[8];
#pragma unroll
    for (int j = 0; j < 8; j++) a[j] = 0.f;

    for (int kk = 0; kk < 64; kk++) {
        float zk = Zs[kk * 65 + lane];
        const float4* w4 = (const float4*)(wcol + kk * 64);
        float4 wa = w4[0], wb = w4[1];
        a[0] += zk * wa.x; a[1] += zk * wa.y; a[2] += zk * wa.z; a[3] += zk * wa.w;
        a[4] += zk * wb.x; a[5] += zk * wb.y; a[6] += zk * wb.z; a[7] += zk * wb.w;
    }

    // stash bf16 pairs to LDS for the packed-transpose store
    unsigned int u0 = (unsigned int)f2bf(a[0]) | ((unsigned int)f2bf(a[1]) << 16);
    unsigned int u1 = (unsigned int)f2bf(a[2]) | ((unsigned int)f2bf(a[3]) << 16);
    unsigned int u2 = (unsigned int)f2bf(a[4]) | ((unsigned int)f2bf(a[5]) << 16);
    unsigned int u3 = (unsigned int)f2bf(a[6]) | ((unsigned int)f2bf(a[7]) << 16);
    Hs[lane * 33 + cg * 4 + 0] = u0;
    Hs[lane * 33 + cg * 4 + 1] = u1;
    Hs[lane * 33 + cg * 4 + 2] = u2;
    Hs[lane * 33 + cg * 4 + 3] = u3;

    int head = cg >> 1, seg = (cg & 1) * 8;
    const float* as = a_src + head * 16 + seg;
    const float* ad = a_dst + head * 16 + seg;
    float ps = a[0]*as[0] + a[1]*as[1] + a[2]*as[2] + a[3]*as[3]
             + a[4]*as[4] + a[5]*as[5] + a[6]*as[6] + a[7]*as[7];
    float pd = a[0]*ad[0] + a[1]*ad[1] + a[2]*ad[2] + a[3]*ad[3]
             + a[4]*ad[4] + a[5]*ad[5] + a[6]*ad[6] + a[7]*ad[7];
    Ps[cg][lane] = ps;
    Pd[cg][lane] = pd;
    __syncthreads();

    if (cg < 4) {
        int tn = row0 + lane;
        float sv = (Ps[2 * cg][lane] + Ps[2 * cg + 1][lane]) * LOG2E;
        float dv = (Pd[2 * cg][lane] + Pd[2 * cg + 1][lane]) * LOG2E;
        est[(size_t)tn * 4 + cg] = sv;     // == [n*64 + b*4 + head]
        edt[(size_t)tn * 4 + cg] = dv;
    }

    // packed ht store: thread t handles (n', bg, col-pair)
    {
        int nbg = t >> 5;                  // 0..15: n' = nbg>>2, bg = nbg&3
        int np = nbg >> 2, bg = nbg & 3;
        int cp = t & 31;                   // col-pair index, c0 = 2*cp
        int rbase = np * 16 + bg * 4;
        unsigned int r0 = Hs[(rbase + 0) * 33 + cp];
        unsigned int r1 = Hs[(rbase + 1) * 33 + cp];
        unsigned int r2 = Hs[(rbase + 2) * 33 + cp];
        unsigned int r3 = Hs[(rbase + 3) * 33 + cp];
        uint4 o;
        o.x = (r0 & 0xffffu) | (r1 << 16);          // c0: batches 0,1
        o.y = (r2 & 0xffffu) | (r3 << 16);          // c0: batches 2,3
        o.z = (r0 >> 16) | (r1 & 0xffff0000u);      // c0+1: batches 0,1
        o.w = (r2 >> 16) | (r3 & 0xffff0000u);      // c0+1: batches 2,3
        int ng = blockIdx.x * 4 + np;
        *(uint4*)((unsigned int*)ht4 + (((size_t)(ng * 4 + bg)) * 64 + 2 * cp) * 2) = o;
    }
}

// ---------------- per-node softmax aggregation ----------------
// Block = 1 node, 4 waves; wave bg handles batches bg*4..bg*4+3; lane = column c.
__global__ __launch_bounds__(256) void gat_agg_k(
    const uint2* __restrict__ ht4, const float* __restrict__ est, const float* __restrict__ edt,
    const int* __restrict__ offs, const int* __restrict__ csr,
    const float* __restrict__ bias_g, float* __restrict__ kout)
{
    int n = blockIdx.x;                               // node
    int bg = threadIdx.x >> 6;                        // batch group (4 batches)
    int lane = threadIdx.x & 63;
    int hd = lane >> 4;                               // head for this column
    int o0 = offs[n], o1 = offs[n + 1];

    int eoff = bg * 16 + (lane & 15);                 // score slot for this lane
    float edv = edt[(size_t)n * 64 + eoff];
    const uint2* hbase = ht4 + (size_t)bg * 64 + lane;

    float d0 = 0.f, d1 = 0.f, d2 = 0.f, d3 = 0.f;
    float a0 = 0.f, a1 = 0.f, a2 = 0.f, a3 = 0.f;

    for (int base = o0; base < o1; base += 64) {
        int cnt = o1 - base; if (cnt > 64) cnt = 64;
        int sv = csr[base + (lane < cnt ? lane : cnt - 1)];
#pragma unroll 2
        for (int j = 0; j < cnt; j++) {
            int s = __builtin_amdgcn_readlane(sv, j);
            float esv = est[(size_t)s * 64 + eoff];
            float e = esv + edv;
            e = fmaxf(e, 0.2f * e);                   // leaky_relu (slope<1, scaled log2e)
            float w = fexp2(e);
            float w0 = __shfl(w, hd);
            float w1 = __shfl(w, 4 + hd);
            float w2 = __shfl(w, 8 + hd);
            float w3 = __shfl(w, 12 + hd);
            uint2 hv = hbase[(size_t)s * 256];
            float h0 = __uint_as_float(hv.x << 16);
            float h1 = __uint_as_float(hv.x & 0xffff0000u);
            float h2 = __uint_as_float(hv.y << 16);
            float h3 = __uint_as_float(hv.y & 0xffff0000u);
            d0 += w0; a0 += w0 * h0;
            d1 += w1; a1 += w1 * h1;
            d2 += w2; a2 += w2 * h2;
            d3 += w3; a3 += w3 * h3;
        }
    }
    float bg_b = bias_g[lane];
    bool has = (o1 > o0);
    float r0 = has ? __builtin_amdgcn_rcpf(d0) : 0.f;
    float r1 = has ? __builtin_amdgcn_rcpf(d1) : 0.f;
    float r2 = has ? __builtin_amdgcn_rcpf(d2) : 0.f;
    float r3 = has ? __builtin_amdgcn_rcpf(d3) : 0.f;
    float* kp = kout + ((size_t)n * 16 + bg * 4) * 64 + lane;
    kp[0]   = a0 * r0 + bg_b;
    kp[64]  = a1 * r1 + bg_b;
    kp[128] = a2 * r2 + bg_b;
    kp[192] = a3 * r3 + bg_b;
}

// ---------------- final: y' = y + dt/6(acc+k4); out = tanh(y'@w1+b1)@w2+b2 ----------------
__global__ __launch_bounds__(256) void mlp_k(
    const float* __restrict__ yin, const float* __restrict__ kc, const float* __restrict__ acc,
    const float* __restrict__ w1, const float* __restrict__ b1,
    const float* __restrict__ w2, const float* __restrict__ b2,
    float* __restrict__ out)
{
    __shared__ float Zs[64 * 65];
    __shared__ float Ts[64 * 65];
    int t = threadIdx.x;
    int row0 = blockIdx.x * 64;
    const float4* y4 = (const float4*)(yin + (size_t)row0 * 64);
    const float4* k4 = (const float4*)(kc + (size_t)row0 * 64);
    const float4* a4 = (const float4*)(acc + (size_t)row0 * 64);
#pragma unroll
    for (int i = 0; i < 4; i++) {
        int flat = t + 256 * i;
        float4 z = y4[flat];
        float4 kv = k4[flat];
        float4 av = a4[flat];
        z.x += DT6C * (av.x + kv.x); z.y += DT6C * (av.y + kv.y);
        z.z += DT6C * (av.z + kv.z); z.w += DT6C * (av.w + kv.w);
        int r = flat >> 4;
        int kkb = (flat & 15) << 2;
        Zs[(kkb + 0) * 65 + r] = z.x;
        Zs[(kkb + 1) * 65 + r] = z.y;
        Zs[(kkb + 2) * 65 + r] = z.z;
        Zs[(kkb + 3) * 65 + r] = z.w;
    }
    __syncthreads();

    int lane = t & 63;
    int g = __builtin_amdgcn_readfirstlane(t >> 6);
    float a[16];
#pragma unroll
    for (int j = 0; j < 16; j++) a[j] = 0.f;
    const float* w1g = w1 + g * 16;
    for (int kk = 0; kk < 64; kk++) {
        float zk = Zs[kk * 65 + lane];
        const float4* w4 = (const float4*)(w1g + kk * 64);
        float4 w0 = w4[0], w1v = w4[1], w2v = w4[2], w3v = w4[3];
        a[0] += zk * w0.x;  a[1] += zk * w0.y;  a[2] += zk * w0.z;  a[3] += zk * w0.w;
        a[4] += zk * w1v.x; a[5] += zk * w1v.y; a[6] += zk * w1v.z; a[7] += zk * w1v.w;
        a[8] += zk * w2v.x; a[9] += zk * w2v.y; a[10] += zk * w2v.z; a[11] += zk * w2v.w;
        a[12] += zk * w3v.x; a[13] += zk * w3v.y; a[14] += zk * w3v.z; a[15] += zk * w3v.w;
    }
    const float4* b1g = (const float4*)(b1 + g * 16);
    float4 bb0 = b1g[0], bb1 = b1g[1], bb2 = b1g[2], bb3 = b1g[3];
    float bb[16] = { bb0.x,bb0.y,bb0.z,bb0.w, bb1.x,bb1.y,bb1.z,bb1.w,
                     bb2.x,bb2.y,bb2.z,bb2.w, bb3.x,bb3.y,bb3.z,bb3.w };
#pragma unroll
    for (int j = 0; j < 16; j++) {
        float v = a[j] + bb[j];
        float ex = __expf(2.f * v);
        float tv = 1.f - 2.f / (ex + 1.f);
        Ts[(16 * g + j) * 65 + lane] = tv;
    }
    __syncthreads();

    float a2[16];
#pragma unroll
    for (int j = 0; j < 16; j++) a2[j] = 0.f;
    const float* w2g = w2 + g * 16;
    for (int kk = 0; kk < 64; kk++) {
        float tk = Ts[kk * 65 + lane];
        const float4* w4 = (const float4*)(w2g + kk * 64);
        float4 w0 = w4[0], w1v = w4[1], w2v = w4[2], w3v = w4[3];
        a2[0] += tk * w0.x;  a2[1] += tk * w0.y;  a2[2] += tk * w0.z;  a2[3] += tk * w0.w;
        a2[4] += tk * w1v.x; a2[5] += tk * w1v.y; a2[6] += tk * w1v.z; a2[7] += tk * w1v.w;
        a2[8] += tk * w2v.x; a2[9] += tk * w2v.y; a2[10] += tk * w2v.z; a2[11] += tk * w2v.w;
        a2[12] += tk * w3v.x; a2[13] += tk * w3v.y; a2[14] += tk * w3v.z; a2[15] += tk * w3v.w;
    }
    const float4* b2g = (const float4*)(b2 + g * 16);
    float4 c0 = b2g[0], c1 = b2g[1], c2 = b2g[2], c3 = b2g[3];
    int tn = row0 + lane;
    int n = tn >> 4, b = tn & 15;
    float4* o4 = (float4*)(out + ((size_t)b * NN + n) * 64 + g * 16);
    o4[0] = make_float4(a2[0] + c0.x, a2[1] + c0.y, a2[2] + c0.z, a2[3] + c0.w);
    o4[1] = make_float4(a2[4] + c1.x, a2[5] + c1.y, a2[6] + c1.z, a2[7] + c1.w);
    o4[2] = make_float4(a2[8] + c2.x, a2[9] + c2.y, a2[10] + c2.z, a2[11] + c2.w);
    o4[3] = make_float4(a2[12] + c3.x, a2[13] + c3.y, a2[14] + c3.z, a2[15] + c3.w);
}

extern "C" void kernel_launch(void* const* d_in, const int* in_sizes, int n_in,
                              void* d_out, int out_size, void* d_ws, size_t ws_size,
                              hipStream_t stream)
{
    const float* inputs = (const float*)d_in[0];
    const float* w_in   = (const float*)d_in[1];
    const float* b_in   = (const float*)d_in[2];
    const float* Wh     = (const float*)d_in[3];
    const float* bias_g = (const float*)d_in[4];
    const float* a_src  = (const float*)d_in[5];
    const float* a_dst  = (const float*)d_in[6];
    const float* w1     = (const float*)d_in[7];
    const float* b1     = (const float*)d_in[8];
    const float* w2     = (const float*)d_in[9];
    const float* b2     = (const float*)d_in[10];
    const int* src      = (const int*)d_in[11];
    const int* dst      = (const int*)d_in[12];
    float* out = (float*)d_out;

    float* ws = (float*)d_ws;
    const size_t SZ = (size_t)NROWS * 64;          // 2097152 floats (8 MB)
    float* y   = ws;
    float* acc = y + SZ;
    float* kc  = acc + SZ;
    uint2* ht4 = (uint2*)(kc + SZ);                // SZ bf16 = 4 MB
    float* est = (float*)((unsigned short*)ht4 + SZ);
    float* edt = est + (size_t)NROWS * 4;
    int* offs   = (int*)(edt + (size_t)NROWS * 4); // 2049 used
    int* cursor = offs + 2064;
    int* deg    = cursor + 2048;
    int* csr    = deg + 2048;                      // NE ints

    init_y_k<<<NROWS * 64 / 256, 256, 0, stream>>>(inputs, w_in, b_in, y);
    zero_deg_k<<<8, 256, 0, stream>>>(deg);
    count_deg_k<<<NE / 256, 256, 0, stream>>>(dst, deg);
    scan_k<<<1, 1024, 0, stream>>>(deg, offs, cursor);
    scatter_k<<<NE / 256, 256, 0, stream>>>(src, dst, cursor, csr);

    for (int step = 0; step < 12; step++) {
        gemm_k<<<512, 512, 0, stream>>>(y, kc, acc, y, Wh, a_src, a_dst, ht4, est, edt, step == 0 ? 0 : 4);
        gat_agg_k<<<NN, 256, 0, stream>>>(ht4, est, edt, offs, csr, bias_g, kc);   // k1
        gemm_k<<<512, 512, 0, stream>>>(y, kc, acc, y, Wh, a_src, a_dst, ht4, est, edt, 1);
        gat_agg_k<<<NN, 256, 0, stream>>>(ht4, est, edt, offs, csr, bias_g, kc);   // k2
        gemm_k<<<512, 512, 0, stream>>>(y, kc, acc, y, Wh, a_src, a_dst, ht4, est, edt, 2);
        gat_agg_k<<<NN, 256, 0, stream>>>(ht4, est, edt, offs, csr, bias_g, kc);   // k3
        gemm_k<<<512, 512, 0, stream>>>(y, kc, acc, y, Wh, a_src, a_dst, ht4, est, edt, 3);
        gat_agg_k<<<NN, 256, 0, stream>>>(ht4, est, edt, offs, csr, bias_g, kc);   // k4
    }
    mlp_k<<<512, 256, 0, stream>>>(y, kc, acc, w1, b1, w2, b2, out);
}

// Round 5
// 1053.577 us; speedup vs baseline: 3.6512x; 1.5025x over previous
//
#include <hip/hip_runtime.h>

#define NB 16
#define NS 12
#define NN 2048
#define NE 32768
#define NROWS (NB*NN)          // 32768 rows of 64
#define DTC  0.1f
#define DT2C 0.05f
#define DT6C (0.1f/6.0f)
#define LOG2E 1.44269504088896f

// Node-major state: row tn = n*16 + b.
// ht packed: uint2 at [(n*4+bg)*64 + c] = bf16 h for batches bg*4..bg*4+3, column c.
// est/edt: [n*64 + b*4 + head], pre-scaled by LOG2E.
// ht/est/edt are DOUBLE-BUFFERED across fused evals (read old, write new).

__device__ __forceinline__ unsigned short f2bf(float f) {
    unsigned int u = __float_as_uint(f);
    u = u + 0x7fffu + ((u >> 16) & 1u);      // RTNE
    return (unsigned short)(u >> 16);
}
__device__ __forceinline__ float fexp2(float x) {
#if __has_builtin(__builtin_amdgcn_exp2f)
    return __builtin_amdgcn_exp2f(x);
#else
    return __expf(x * 0.69314718056f);
#endif
}

// ---------------- init: y0 = inputs[:,0] @ w_in + b_in (node-major out) ----------------
__global__ __launch_bounds__(256) void init_y_k(const float* __restrict__ inputs,
    const float* __restrict__ w_in, const float* __restrict__ b_in, float* __restrict__ y)
{
    int idx = blockIdx.x * 256 + threadIdx.x;     // < NROWS*64
    int hh = idx & 63;
    int tn = idx >> 6;
    int n = tn >> 4, b = tn & 15;
    const float* ip = inputs + ((size_t)(b * NS) * NN + n) * 2;
    y[idx] = ip[0] * w_in[hh] + ip[1] * w_in[64 + hh] + b_in[hh];
}

// ---------------- CSR build (once per launch) ----------------
__global__ __launch_bounds__(256) void zero_deg_k(int* __restrict__ deg)
{
    int i = blockIdx.x * 256 + threadIdx.x;
    if (i < NN) deg[i] = 0;
}
__global__ __launch_bounds__(256) void count_deg_k(const int* __restrict__ dst, int* __restrict__ deg)
{
    int e = blockIdx.x * 256 + threadIdx.x;
    if (e < NE) atomicAdd(&deg[dst[e]], 1);
}
__global__ __launch_bounds__(1024) void scan_k(const int* __restrict__ deg,
    int* __restrict__ offs, int* __restrict__ cursor)
{
    __shared__ int p[1024];
    int t = threadIdx.x;
    int d0 = deg[2 * t], d1 = deg[2 * t + 1];
    p[t] = d0 + d1;
    __syncthreads();
    for (int d = 1; d < 1024; d <<= 1) {
        int v = (t >= d) ? p[t - d] : 0;
        __syncthreads();
        p[t] += v;
        __syncthreads();
    }
    int excl = (t > 0) ? p[t - 1] : 0;     // exclusive pair-sum
    offs[2 * t] = excl;       offs[2 * t + 1] = excl + d0;
    cursor[2 * t] = excl;     cursor[2 * t + 1] = excl + d0;
    if (t == 1023) offs[2048] = p[1023];
}
__global__ __launch_bounds__(256) void scatter_k(const int* __restrict__ src, const int* __restrict__ dst,
    int* __restrict__ cursor, int* __restrict__ csr)
{
    int e = blockIdx.x * 256 + threadIdx.x;
    if (e < NE) {
        int pos = atomicAdd(&cursor[dst[e]], 1);
        csr[pos] = src[e];
    }
}

// ---------------- FUSED: agg(prev eval) -> k (LDS) -> RK combine -> gemm(z) ----------------
// Block = 64 rows (4 nodes x 16 batches), 1024 threads = 16 waves.
// mode 0: no agg; z = y                        (very first eval)
// mode 1: agg->k1; z = y + 0.5dt*k ; acc  = k
// mode 2: agg->k2; z = y + 0.5dt*k ; acc += 2k
// mode 3: agg->k3; z = y + dt*k    ; acc += 2k
// mode 4: agg->k4; y = y + dt/6*(acc+k); z = y  (stage1 of next step)
// mode 5: agg->k4; y = y + dt/6*(acc+k); stop  (final, no gemm)
__global__ __launch_bounds__(1024, 8) void fused_k(
    const float* yin, float* __restrict__ acc, float* yout,
    const uint2* __restrict__ htR, const float* __restrict__ estR, const float* __restrict__ edtR,
    uint2* __restrict__ htW, float* __restrict__ estW, float* __restrict__ edtW,
    const int* __restrict__ offs, const int* __restrict__ csr, const float* __restrict__ bias_g,
    const float* __restrict__ Wh, const float* __restrict__ a_src, const float* __restrict__ a_dst,
    int mode)
{
    __shared__ float kvs[64 * 64];             // k values for my 64 rows (never global)
    __shared__ float Zs[64 * 65];              // Zs[k][r], pad 65
    __shared__ unsigned int Hs[64 * 33];       // bf16-pair matrix [row][colpair], pad 33
    __shared__ float Ps[16][64];
    __shared__ float Pd[16][64];

    int t = threadIdx.x;
    int lane = t & 63;
    int wid = __builtin_amdgcn_readfirstlane(t >> 6);   // wave id / col-group, 0..15

    // ---------- phase 1: aggregation for my 4 nodes (mode != 0) ----------
    if (mode != 0) {
        int np = wid >> 2, bg = wid & 3;
        int n = blockIdx.x * 4 + np;
        int hd = lane >> 4;
        int o0 = offs[n], o1 = offs[n + 1];
        int eoff = bg * 16 + (lane & 15);
        float edv = edtR[(size_t)n * 64 + eoff];
        const uint2* hbase = htR + (size_t)bg * 64 + lane;

        float d0 = 0.f, d1 = 0.f, d2 = 0.f, d3 = 0.f;
        float a0 = 0.f, a1 = 0.f, a2 = 0.f, a3 = 0.f;
        for (int base = o0; base < o1; base += 64) {
            int cnt = o1 - base; if (cnt > 64) cnt = 64;
            int svv = csr[base + (lane < cnt ? lane : cnt - 1)];
#pragma unroll 2
            for (int j = 0; j < cnt; j++) {
                int s = __builtin_amdgcn_readlane(svv, j);
                float esv = estR[(size_t)s * 64 + eoff];
                float e = esv + edv;
                e = fmaxf(e, 0.2f * e);                   // leaky_relu (slope<1, log2e-scaled)
                float w = fexp2(e);
                float w0 = __shfl(w, hd);
                float w1 = __shfl(w, 4 + hd);
                float w2 = __shfl(w, 8 + hd);
                float w3 = __shfl(w, 12 + hd);
                uint2 hv = hbase[(size_t)s * 256];
                float h0 = __uint_as_float(hv.x << 16);
                float h1 = __uint_as_float(hv.x & 0xffff0000u);
                float h2 = __uint_as_float(hv.y << 16);
                float h3 = __uint_as_float(hv.y & 0xffff0000u);
                d0 += w0; a0 += w0 * h0;
                d1 += w1; a1 += w1 * h1;
                d2 += w2; a2 += w2 * h2;
                d3 += w3; a3 += w3 * h3;
            }
        }
        float bgb = bias_g[lane];
        bool has = (o1 > o0);
        float r0 = has ? __builtin_amdgcn_rcpf(d0) : 0.f;
        float r1 = has ? __builtin_amdgcn_rcpf(d1) : 0.f;
        float r2 = has ? __builtin_amdgcn_rcpf(d2) : 0.f;
        float r3 = has ? __builtin_amdgcn_rcpf(d3) : 0.f;
        int rb = np * 16 + bg * 4;
        kvs[(rb + 0) * 64 + lane] = a0 * r0 + bgb;
        kvs[(rb + 1) * 64 + lane] = a1 * r1 + bgb;
        kvs[(rb + 2) * 64 + lane] = a2 * r2 + bgb;
        kvs[(rb + 3) * 64 + lane] = a3 * r3 + bgb;
        __syncthreads();                       // mode is launch-uniform: safe
    }

    // ---------- phase 2: RK combine + stage z to LDS ----------
    int row0 = blockIdx.x * 64;
    const float4* y4 = (const float4*)(yin + (size_t)row0 * 64);
    float4* a4g = (float4*)(acc + (size_t)row0 * 64);
    float4* yo4 = (float4*)(yout + (size_t)row0 * 64);
    int flat = t;                              // float4 index, 0..1023
    float4 z = y4[flat];
    if (mode >= 1) {
        float4 kf = *(const float4*)&kvs[flat * 4];   // == kvs[row*64 + quad*4]
        if (mode == 1) {
            a4g[flat] = kf;
            z.x += DT2C * kf.x; z.y += DT2C * kf.y; z.z += DT2C * kf.z; z.w += DT2C * kf.w;
        } else if (mode == 2) {
            float4 av = a4g[flat];
            av.x += 2.f * kf.x; av.y += 2.f * kf.y; av.z += 2.f * kf.z; av.w += 2.f * kf.w;
            a4g[flat] = av;
            z.x += DT2C * kf.x; z.y += DT2C * kf.y; z.z += DT2C * kf.z; z.w += DT2C * kf.w;
        } else if (mode == 3) {
            float4 av = a4g[flat];
            av.x += 2.f * kf.x; av.y += 2.f * kf.y; av.z += 2.f * kf.z; av.w += 2.f * kf.w;
            a4g[flat] = av;
            z.x += DTC * kf.x; z.y += DTC * kf.y; z.z += DTC * kf.z; z.w += DTC * kf.w;
        } else {                               // mode 4 or 5
            float4 av = a4g[flat];
            z.x += DT6C * (av.x + kf.x); z.y += DT6C * (av.y + kf.y);
            z.z += DT6C * (av.z + kf.z); z.w += DT6C * (av.w + kf.w);
            yo4[flat] = z;
        }
    }
    if (mode == 5) return;                     // final eval: y written, no gemm

    {
        int r = flat >> 4;
        int kkb = (flat & 15) << 2;
        Zs[(kkb + 0) * 65 + r] = z.x;
        Zs[(kkb + 1) * 65 + r] = z.y;
        Zs[(kkb + 2) * 65 + r] = z.z;
        Zs[(kkb + 3) * 65 + r] = z.w;
    }
    __syncthreads();

    // ---------- phase 3: gemm, 4 cols/thread ----------
    const float* wcol = Wh + wid * 4;
    float a0 = 0.f, a1 = 0.f, a2 = 0.f, a3 = 0.f;
    for (int kk = 0; kk < 64; kk++) {
        float zk = Zs[kk * 65 + lane];
        const float4* w4 = (const float4*)(wcol + kk * 64);
        float4 w = w4[0];
        a0 += zk * w.x; a1 += zk * w.y; a2 += zk * w.z; a3 += zk * w.w;
    }

    // ---------- phase 4: epilogue ----------
    Hs[lane * 33 + wid * 2 + 0] = (unsigned int)f2bf(a0) | ((unsigned int)f2bf(a1) << 16);
    Hs[lane * 33 + wid * 2 + 1] = (unsigned int)f2bf(a2) | ((unsigned int)f2bf(a3) << 16);

    int head = wid >> 2, qp = wid & 3;
    const float* as = a_src + head * 16 + qp * 4;
    const float* ad = a_dst + head * 16 + qp * 4;
    Ps[wid][lane] = a0 * as[0] + a1 * as[1] + a2 * as[2] + a3 * as[3];
    Pd[wid][lane] = a0 * ad[0] + a1 * ad[1] + a2 * ad[2] + a3 * ad[3];
    __syncthreads();

    if (wid < 4) {                             // head = wid
        int tn = row0 + lane;
        float sv = (Ps[wid * 4 + 0][lane] + Ps[wid * 4 + 1][lane]
                  + Ps[wid * 4 + 2][lane] + Ps[wid * 4 + 3][lane]) * LOG2E;
        float dv = (Pd[wid * 4 + 0][lane] + Pd[wid * 4 + 1][lane]
                  + Pd[wid * 4 + 2][lane] + Pd[wid * 4 + 3][lane]) * LOG2E;
        estW[(size_t)tn * 4 + wid] = sv;       // == [n*64 + b*4 + head]
        edtW[(size_t)tn * 4 + wid] = dv;
    }

    if (t < 512) {                             // packed ht store (wave-uniform branch)
        int nbg = t >> 5;                      // 0..15
        int np = nbg >> 2, bg = nbg & 3;
        int cp = t & 31;
        int rbase = np * 16 + bg * 4;
        unsigned int r0 = Hs[(rbase + 0) * 33 + cp];
        unsigned int r1 = Hs[(rbase + 1) * 33 + cp];
        unsigned int r2 = Hs[(rbase + 2) * 33 + cp];
        unsigned int r3 = Hs[(rbase + 3) * 33 + cp];
        uint4 o;
        o.x = (r0 & 0xffffu) | (r1 << 16);
        o.y = (r2 & 0xffffu) | (r3 << 16);
        o.z = (r0 >> 16) | (r1 & 0xffff0000u);
        o.w = (r2 >> 16) | (r3 & 0xffff0000u);
        int ng = blockIdx.x * 4 + np;
        *(uint4*)((unsigned int*)htW + (((size_t)(ng * 4 + bg)) * 64 + 2 * cp) * 2) = o;
    }
}

// ---------------- final MLP: out = tanh(y@w1+b1)@w2+b2 (y precombined) ----------------
__global__ __launch_bounds__(256) void mlp_k(
    const float* __restrict__ yin,
    const float* __restrict__ w1, const float* __restrict__ b1,
    const float* __restrict__ w2, const float* __restrict__ b2,
    float* __restrict__ out)
{
    __shared__ float Zs[64 * 65];
    __shared__ float Ts[64 * 65];
    int t = threadIdx.x;
    int row0 = blockIdx.x * 64;
    const float4* y4 = (const float4*)(yin + (size_t)row0 * 64);
#pragma unroll
    for (int i = 0; i < 4; i++) {
        int flat = t + 256 * i;
        float4 z = y4[flat];
        int r = flat >> 4;
        int kkb = (flat & 15) << 2;
        Zs[(kkb + 0) * 65 + r] = z.x;
        Zs[(kkb + 1) * 65 + r] = z.y;
        Zs[(kkb + 2) * 65 + r] = z.z;
        Zs[(kkb + 3) * 65 + r] = z.w;
    }
    __syncthreads();

    int lane = t & 63;
    int g = __builtin_amdgcn_readfirstlane(t >> 6);
    float a[16];
#pragma unroll
    for (int j = 0; j < 16; j++) a[j] = 0.f;
    const float* w1g = w1 + g * 16;
    for (int kk = 0; kk < 64; kk++) {
        float zk = Zs[kk * 65 + lane];
        const float4* w4 = (const float4*)(w1g + kk * 64);
        float4 w0 = w4[0], w1v = w4[1], w2v = w4[2], w3v = w4[3];
        a[0] += zk * w0.x;  a[1] += zk * w0.y;  a[2] += zk * w0.z;  a[3] += zk * w0.w;
        a[4] += zk * w1v.x; a[5] += zk * w1v.y; a[6] += zk * w1v.z; a[7] += zk * w1v.w;
        a[8] += zk * w2v.x; a[9] += zk * w2v.y; a[10] += zk * w2v.z; a[11] += zk * w2v.w;
        a[12] += zk * w3v.x; a[13] += zk * w3v.y; a[14] += zk * w3v.z; a[15] += zk * w3v.w;
    }
    const float4* b1g = (const float4*)(b1 + g * 16);
    float4 bb0 = b1g[0], bb1 = b1g[1], bb2 = b1g[2], bb3 = b1g[3];
    float bb[16] = { bb0.x,bb0.y,bb0.z,bb0.w, bb1.x,bb1.y,bb1.z,bb1.w,
                     bb2.x,bb2.y,bb2.z,bb2.w, bb3.x,bb3.y,bb3.z,bb3.w };
#pragma unroll
    for (int j = 0; j < 16; j++) {
        float v = a[j] + bb[j];
        float ex = __expf(2.f * v);
        float tv = 1.f - 2.f / (ex + 1.f);
        Ts[(16 * g + j) * 65 + lane] = tv;
    }
    __syncthreads();

    float a2[16];
#pragma unroll
    for (int j = 0; j < 16; j++) a2[j] = 0.f;
    const float* w2g = w2 + g * 16;
    for (int kk = 0; kk < 64; kk++) {
        float tk = Ts[kk * 65 + lane];
        const float4* w4 = (const float4*)(w2g + kk * 64);
        float4 w0 = w4[0], w1v = w4[1], w2v = w4[2], w3v = w4[3];
        a2[0] += tk * w0.x;  a2[1] += tk * w0.y;  a2[2] += tk * w0.z;  a2[3] += tk * w0.w;
        a2[4] += tk * w1v.x; a2[5] += tk * w1v.y; a2[6] += tk * w1v.z; a2[7] += tk * w1v.w;
        a2[8] += tk * w2v.x; a2[9] += tk * w2v.y; a2[10] += tk * w2v.z; a2[11] += tk * w2v.w;
        a2[12] += tk * w3v.x; a2[13] += tk * w3v.y; a2[14] += tk * w3v.z; a2[15] += tk * w3v.w;
    }
    const float4* b2g = (const float4*)(b2 + g * 16);
    float4 c0 = b2g[0], c1 = b2g[1], c2 = b2g[2], c3 = b2g[3];
    int tn = row0 + lane;
    int n = tn >> 4, b = tn & 15;
    float4* o4 = (float4*)(out + ((size_t)b * NN + n) * 64 + g * 16);
    o4[0] = make_float4(a2[0] + c0.x, a2[1] + c0.y, a2[2] + c0.z, a2[3] + c0.w);
    o4[1] = make_float4(a2[4] + c1.x, a2[5] + c1.y, a2[6] + c1.z, a2[7] + c1.w);
    o4[2] = make_float4(a2[8] + c2.x, a2[9] + c2.y, a2[10] + c2.z, a2[11] + c2.w);
    o4[3] = make_float4(a2[12] + c3.x, a2[13] + c3.y, a2[14] + c3.z, a2[15] + c3.w);
}

extern "C" void kernel_launch(void* const* d_in, const int* in_sizes, int n_in,
                              void* d_out, int out_size, void* d_ws, size_t ws_size,
                              hipStream_t stream)
{
    const float* inputs = (const float*)d_in[0];
    const float* w_in   = (const float*)d_in[1];
    const float* b_in   = (const float*)d_in[2];
    const float* Wh     = (const float*)d_in[3];
    const float* bias_g = (const float*)d_in[4];
    const float* a_src  = (const float*)d_in[5];
    const float* a_dst  = (const float*)d_in[6];
    const float* w1     = (const float*)d_in[7];
    const float* b1     = (const float*)d_in[8];
    const float* w2     = (const float*)d_in[9];
    const float* b2     = (const float*)d_in[10];
    const int* src      = (const int*)d_in[11];
    const int* dst      = (const int*)d_in[12];
    float* out = (float*)d_out;

    float* ws = (float*)d_ws;
    const size_t SZ = (size_t)NROWS * 64;          // 2097152 floats (8 MB)
    float* y   = ws;
    float* acc = y + SZ;
    // double-buffered ht/est/edt
    uint2* htA = (uint2*)(acc + SZ);               // SZ bf16 = 4 MB
    float* estA = (float*)((unsigned short*)htA + SZ);
    float* edtA = estA + (size_t)NROWS * 4;
    uint2* htB = (uint2*)(edtA + (size_t)NROWS * 4);
    float* estB = (float*)((unsigned short*)htB + SZ);
    float* edtB = estB + (size_t)NROWS * 4;
    int* offs   = (int*)(edtB + (size_t)NROWS * 4);
    int* cursor = offs + 2064;
    int* deg    = cursor + 2048;
    int* csr    = deg + 2048;                      // NE ints

    init_y_k<<<NROWS * 64 / 256, 256, 0, stream>>>(inputs, w_in, b_in, y);
    zero_deg_k<<<8, 256, 0, stream>>>(deg);
    count_deg_k<<<NE / 256, 256, 0, stream>>>(dst, deg);
    scan_k<<<1, 1024, 0, stream>>>(deg, offs, cursor);
    scatter_k<<<NE / 256, 256, 0, stream>>>(src, dst, cursor, csr);

    uint2* htR = htA;  float* estR = estA; float* edtR = edtA;
    uint2* htW = htB;  float* estW = estB; float* edtW = edtB;

    // eval #0: no agg, z = y, gemm -> buffer A
    fused_k<<<512, 1024, 0, stream>>>(y, acc, y, htB, estB, edtB, htA, estA, edtA,
                                      offs, csr, bias_g, Wh, a_src, a_dst, 0);
    for (int step = 0; step < 12; step++) {
        for (int st = 1; st <= 4; st++) {
            int mode = (step == 11 && st == 4) ? 5 : st;
            fused_k<<<512, 1024, 0, stream>>>(y, acc, y, htR, estR, edtR, htW, estW, edtW,
                                              offs, csr, bias_g, Wh, a_src, a_dst, mode);
            // swap buffers
            uint2* th = htR; htR = htW; htW = th;
            float* te = estR; estR = estW; estW = te;
            float* td = edtR; edtR = edtW; edtW = td;
        }
    }
    mlp_k<<<512, 256, 0, stream>>>(y, w1, b1, w2, b2, out);
}